// Round 8
// baseline (17653.859 us; speedup 1.0000x reference)
//
#include <hip/hip_runtime.h>
#include <hip/hip_cooperative_groups.h>
#include <cmath>

namespace cg = cooperative_groups;

#define NNODES 20000
#define FD 64
#define EPN 15      // regular edges per node
#define NB 1024     // DEG * F
#define BSUB 80     // subspace width (top-64 + 16 buffer)
#define NCLS 16

// ---------------------------------------------------------------------------
// out[n][o] = relu?( sum_j X[n][j] * W[o][j] + bias[o] ), X: [N,64], W: [ncol,64]
__global__ __launch_bounds__(256) void k_linT(const float* __restrict__ X,
    const float* __restrict__ W, const float* __restrict__ bias,
    float* __restrict__ out, int ncol, int relu)
{
  __shared__ float Wsh[64][65];
  __shared__ float Xsh[64][65];
  int t = threadIdx.x;
  int r0 = blockIdx.x * 64;
  for (int idx = t; idx < ncol * 64; idx += 256) Wsh[idx >> 6][idx & 63] = W[idx];
  for (int idx = t; idx < 64 * 64; idx += 256) {
    int r = idx >> 6, c = idx & 63;
    Xsh[r][c] = (r0 + r < NNODES) ? X[(size_t)(r0 + r) * 64 + c] : 0.f;
  }
  __syncthreads();
  for (int idx = t; idx < 64 * ncol; idx += 256) {
    int r = idx / ncol, o = idx % ncol;
    float acc = 0.f;
    #pragma unroll
    for (int j = 0; j < 64; j++) acc += Xsh[r][j] * Wsh[o][j];
    if (bias) acc += bias[o];
    if (relu) acc = fmaxf(acc, 0.f);
    if (r0 + r < NNODES) out[(size_t)(r0 + r) * ncol + o] = acc;
  }
}

// ---------------------------------------------------------------------------
__global__ __launch_bounds__(256) void k_meanslot(const float* __restrict__ hl,
    const int* __restrict__ src, float* __restrict__ mus)
{
  int k = blockIdx.x;          // slot 0..15
  int part = blockIdx.y;       // 8 parts x 2500 nodes
  int t = threadIdx.x;
  int c = t & 63, sub = t >> 6;
  int d0 = part * 2500;
  float acc = 0.f;
  for (int d = d0 + sub; d < d0 + 2500; d += 4) {
    int row = (k < EPN) ? src[d * EPN + k] : d;
    acc += hl[(size_t)row * 64 + c];
  }
  __shared__ float red[4][64];
  red[sub][c] = acc;
  __syncthreads();
  if (t < 64) {
    float s = red[0][t] + red[1][t] + red[2][t] + red[3][t];
    atomicAdd(&mus[k * 64 + t], s * (1.f / 20000.f));
  }
}

// ---------------------------------------------------------------------------
__global__ __launch_bounds__(256) void k_gram(const float* __restrict__ hl,
    const int* __restrict__ src, const float* __restrict__ mus,
    float* __restrict__ T)
{
  __shared__ float Ash[64][64];
  __shared__ float Bsh[64][64];
  __shared__ float muA[64], muB[64];
  int t = threadIdx.x;
  int pr = blockIdx.x, i = 0, rem = pr;
  for (int ii = 0; ii < 16; ii++) {
    int cnt = 16 - ii;
    if (rem < cnt) { i = ii; break; }
    rem -= cnt;
  }
  int j = i + rem;
  if (t < 64) muA[t] = mus[i * 64 + t];
  else if (t < 128) muB[t - 64] = mus[j * 64 + (t - 64)];
  float acc[4][4] = {};
  int a0 = (t & 15) * 4, b0 = (t >> 4) * 4;
  int d0 = blockIdx.y * 4000, d1 = d0 + 4000;
  for (int dc = d0; dc < d1; dc += 64) {
    __syncthreads();
    for (int item = t; item < 1024; item += 256) {
      int rr = item >> 4, f4 = item & 15;
      int d = dc + rr;
      float4 va = make_float4(0.f, 0.f, 0.f, 0.f);
      float4 vb = va;
      if (d < d1) {
        int ra = (i < EPN) ? src[d * EPN + i] : d;
        int rb = (j < EPN) ? src[d * EPN + j] : d;
        va = ((const float4*)hl)[(size_t)ra * 16 + f4];
        vb = ((const float4*)hl)[(size_t)rb * 16 + f4];
        int cb = f4 * 4;
        va.x -= muA[cb]; va.y -= muA[cb + 1]; va.z -= muA[cb + 2]; va.w -= muA[cb + 3];
        vb.x -= muB[cb]; vb.y -= muB[cb + 1]; vb.z -= muB[cb + 2]; vb.w -= muB[cb + 3];
      }
      ((float4*)&Ash[rr][0])[f4] = va;
      ((float4*)&Bsh[rr][0])[f4] = vb;
    }
    __syncthreads();
    for (int dd = 0; dd < 64; dd++) {
      float av[4], bv[4];
      #pragma unroll
      for (int u = 0; u < 4; u++) av[u] = Ash[dd][a0 + u];
      #pragma unroll
      for (int u = 0; u < 4; u++) bv[u] = Bsh[dd][b0 + u];
      #pragma unroll
      for (int x = 0; x < 4; x++)
        #pragma unroll
        for (int y = 0; y < 4; y++) acc[x][y] += av[x] * bv[y];
    }
  }
  #pragma unroll
  for (int x = 0; x < 4; x++)
    #pragma unroll
    for (int y = 0; y < 4; y++)
      atomicAdd(&T[(size_t)(i * 64 + a0 + x) * NB + (j * 64 + b0 + y)], acc[x][y]);
}

// ---------------------------------------------------------------------------
__global__ __launch_bounds__(256) void k_assembleG(const float* __restrict__ T,
    float* __restrict__ G)
{
  size_t idx = (size_t)blockIdx.x * 256 + threadIdx.x;
  int p = (int)(idx >> 10), q = (int)(idx & 1023);
  int ti = p >> 6, tj = q >> 6;
  float v = (ti <= tj) ? T[idx] : T[((size_t)q << 10) | (size_t)p];
  G[idx] = v * (1.f / 256.f);
}

__global__ void k_cut0(const float* __restrict__ G, double* __restrict__ scal)
{
  __shared__ float red[256];
  float m = 0.f;
  for (int p = threadIdx.x; p < NB; p += 256) m = fmaxf(m, G[(size_t)p * NB + p]);
  red[threadIdx.x] = m;
  __syncthreads();
  for (int s = 128; s; s >>= 1) {
    if (threadIdx.x < s) red[threadIdx.x] = fmaxf(red[threadIdx.x], red[threadIdx.x + s]);
    __syncthreads();
  }
  if (threadIdx.x == 0) scal[0] = 0.9 * (double)red[0];
}

__global__ void k_initS(float* __restrict__ S)
{
  int idx = blockIdx.x * 256 + threadIdx.x;
  if (idx < NB * BSUB) {
    unsigned u = (unsigned)(idx + 1) * 2654435761u;
    u ^= u >> 16; u *= 2246822519u; u ^= u >> 13; u *= 3266489917u; u ^= u >> 16;
    S[idx] = ((float)u * (1.f / 4294967296.f)) - 0.5f;
  }
}

// ---------------------------------------------------------------------------
// Single G@Z step (split-K + in-kernel atomic combine), used for RR Y = G S.
__global__ __launch_bounds__(256) void k_gzfused(const float* __restrict__ G,
    const float* __restrict__ Z, const float* __restrict__ Zp,
    float* __restrict__ P, float* __restrict__ out, int* __restrict__ cnt,
    const double* __restrict__ cptr, float s1, float s2, float s3)
{
  __shared__ float Gs[32][68];
  __shared__ float Zs[64][84];
  __shared__ int lastf;
  int t = threadIdx.x;
  int r0b = blockIdx.x;
  int r0 = r0b * 32;
  int kz = blockIdx.y;
  int cg = t & 15, rg = t >> 4;
  float acc0[5] = {}, acc1[5] = {};
  for (int k0 = kz * 128; k0 < kz * 128 + 128; k0 += 64) {
    __syncthreads();
    #pragma unroll
    for (int s = 0; s < 2; s++) {
      int item = t + s * 256;
      int rr = item >> 4, f4 = item & 15;
      float4 g = ((const float4*)G)[(size_t)(r0 + rr) * 256 + (k0 >> 2) + f4];
      *(float4*)&Gs[rr][f4 * 4] = g;
    }
    #pragma unroll
    for (int s = 0; s < 5; s++) {
      int item = t + s * 256;
      int rr = item / 20, f4 = item % 20;
      float4 z = ((const float4*)Z)[(size_t)(k0 + rr) * 20 + f4];
      *(float4*)&Zs[rr][f4 * 4] = z;
    }
    __syncthreads();
    for (int kk = 0; kk < 64; kk++) {
      float g0 = Gs[rg * 2 + 0][kk];
      float g1 = Gs[rg * 2 + 1][kk];
      float z[5];
      #pragma unroll
      for (int m = 0; m < 5; m++) z[m] = Zs[kk][cg * 5 + m];
      #pragma unroll
      for (int m = 0; m < 5; m++) { acc0[m] += g0 * z[m]; acc1[m] += g1 * z[m]; }
    }
  }
  size_t base = (size_t)kz * (NB * BSUB) + (size_t)(r0 + rg * 2) * BSUB + cg * 5;
  #pragma unroll
  for (int m = 0; m < 5; m++) P[base + m] = acc0[m];
  #pragma unroll
  for (int m = 0; m < 5; m++) P[base + BSUB + m] = acc1[m];
  __threadfence();
  __syncthreads();
  if (t == 0) {
    int old = atomicAdd(&cnt[r0b], 1);
    lastf = (old == 7) ? 1 : 0;
  }
  __syncthreads();
  if (!lastf) return;
  __threadfence();
  float coef = s1;
  if (cptr) coef = s1 * (float)(2.0 / cptr[0]);
  const float4* P4 = (const float4*)P;
  for (int idx = t; idx < 640; idx += 256) {
    size_t o4 = (size_t)r0 * 20 + idx;
    float4 a = P4[o4];
    #pragma unroll
    for (int u = 1; u < 8; u++) {
      float4 b = P4[(size_t)u * 20480 + o4];
      a.x += b.x; a.y += b.y; a.z += b.z; a.w += b.w;
    }
    float4 z = ((const float4*)Z)[o4];
    float4 o;
    o.x = coef * a.x + s2 * z.x;
    o.y = coef * a.y + s2 * z.y;
    o.z = coef * a.z + s2 * z.z;
    o.w = coef * a.w + s2 * z.w;
    if (s3 != 0.f) {
      float4 zp = ((const float4*)Zp)[o4];
      o.x += s3 * zp.x; o.y += s3 * zp.y; o.z += s3 * zp.z; o.w += s3 * zp.w;
    }
    ((float4*)out)[o4] = o;
  }
  __syncthreads();
  if (t == 0) cnt[r0b] = 0;
}

// ---------------------------------------------------------------------------
// Cooperative fused Chebyshev chunk: deg steps of the split-K G@Z recurrence
// in ONE kernel, grid.sync() between steps. 3-buffer rotation; coefficients
// replicate the host sequence exactly:
//   step 0:  out = (2/c)*(G z) - z
//   step s:  out = (4/c)*(G z) - 2 z - zp
// Result lands in bufs[[1,2,0][(deg-1)%3]].
__global__ __launch_bounds__(256) void k_chebchunk(const float* __restrict__ G,
    float* __restrict__ z0, float* __restrict__ z1, float* __restrict__ z2,
    float* __restrict__ P, int* __restrict__ cnt,
    const double* __restrict__ cptr, int deg)
{
  cg::grid_group grid = cg::this_grid();
  __shared__ float Gs[32][68];
  __shared__ float Zs[64][84];
  __shared__ int lastf;
  int t = threadIdx.x;
  int r0b = blockIdx.x;
  int r0 = r0b * 32;
  int kz = blockIdx.y;
  int cg_ = t & 15, rg = t >> 4;
  float twoc = (float)(2.0 / cptr[0]);
  float* bufs[3] = { z0, z1, z2 };
  int ip = 0, ic = 0, io = 1;
  for (int s = 0; s < deg; s++) {
    const float* Z = bufs[ic];
    const float* Zp = bufs[ip];
    float* out = bufs[io];
    float coef = (s == 0) ? twoc : 2.f * twoc;
    float s2 = (s == 0) ? -1.f : -2.f;
    float s3 = (s == 0) ? 0.f : -1.f;
    float acc0[5] = {}, acc1[5] = {};
    for (int k0 = kz * 128; k0 < kz * 128 + 128; k0 += 64) {
      __syncthreads();
      #pragma unroll
      for (int ss = 0; ss < 2; ss++) {
        int item = t + ss * 256;
        int rr = item >> 4, f4 = item & 15;
        float4 g = ((const float4*)G)[(size_t)(r0 + rr) * 256 + (k0 >> 2) + f4];
        *(float4*)&Gs[rr][f4 * 4] = g;
      }
      #pragma unroll
      for (int ss = 0; ss < 5; ss++) {
        int item = t + ss * 256;
        int rr = item / 20, f4 = item % 20;
        float4 z = ((const float4*)Z)[(size_t)(k0 + rr) * 20 + f4];
        *(float4*)&Zs[rr][f4 * 4] = z;
      }
      __syncthreads();
      for (int kk = 0; kk < 64; kk++) {
        float g0 = Gs[rg * 2 + 0][kk];
        float g1 = Gs[rg * 2 + 1][kk];
        float z[5];
        #pragma unroll
        for (int m = 0; m < 5; m++) z[m] = Zs[kk][cg_ * 5 + m];
        #pragma unroll
        for (int m = 0; m < 5; m++) { acc0[m] += g0 * z[m]; acc1[m] += g1 * z[m]; }
      }
    }
    size_t base = (size_t)kz * (NB * BSUB) + (size_t)(r0 + rg * 2) * BSUB + cg_ * 5;
    #pragma unroll
    for (int m = 0; m < 5; m++) P[base + m] = acc0[m];
    #pragma unroll
    for (int m = 0; m < 5; m++) P[base + BSUB + m] = acc1[m];
    __threadfence();
    __syncthreads();
    if (t == 0) {
      int old = atomicAdd(&cnt[r0b], 1);
      lastf = (old == 7) ? 1 : 0;
    }
    __syncthreads();
    if (lastf) {
      const float4* P4 = (const float4*)P;
      for (int idx = t; idx < 640; idx += 256) {
        size_t o4 = (size_t)r0 * 20 + idx;
        float4 a = P4[o4];
        #pragma unroll
        for (int u = 1; u < 8; u++) {
          float4 b = P4[(size_t)u * 20480 + o4];
          a.x += b.x; a.y += b.y; a.z += b.z; a.w += b.w;
        }
        float4 z = ((const float4*)Z)[o4];
        float4 o;
        o.x = coef * a.x + s2 * z.x;
        o.y = coef * a.y + s2 * z.y;
        o.z = coef * a.z + s2 * z.z;
        o.w = coef * a.w + s2 * z.w;
        if (s3 != 0.f) {
          float4 zp = ((const float4*)Zp)[o4];
          o.x += s3 * zp.x; o.y += s3 * zp.y; o.z += s3 * zp.z; o.w += s3 * zp.w;
        }
        ((float4*)out)[o4] = o;
      }
      __syncthreads();
      if (t == 0) cnt[r0b] = 0;
      __threadfence();
    }
    grid.sync();
    if (s == 0) { ip = 0; ic = 1; io = 2; }
    else { int tmp = ip; ip = ic; ic = io; io = tmp; }
  }
}

// C (f64) = S^T S
__global__ void k_syrk(const float* __restrict__ S, double* __restrict__ C)
{
  int idx = blockIdx.x * 256 + threadIdx.x;
  if (idx >= BSUB * BSUB) return;
  int a = idx / BSUB, b = idx % BSUB;
  double acc = 0.0;
  for (int i = 0; i < NB; i++)
    acc += (double)S[(size_t)i * BSUB + a] * (double)S[(size_t)i * BSUB + b];
  C[idx] = acc;
}

// M (f32, f64 accum) = X^T Y
__global__ void k_xty(const float* __restrict__ X, const float* __restrict__ Y,
                      float* __restrict__ M)
{
  int idx = blockIdx.x * 256 + threadIdx.x;
  if (idx >= BSUB * BSUB) return;
  int a = idx / BSUB, b = idx % BSUB;
  double acc = 0.0;
  for (int i = 0; i < NB; i++)
    acc += (double)X[(size_t)i * BSUB + a] * (double)Y[(size_t)i * BSUB + b];
  M[idx] = (float)acc;
}

// ---------------------------------------------------------------------------
// fused Cholesky (f64, LDS, deferred scaling: 1 barrier/column) + triangular
// inverse -> Rinv (f32).
__global__ __launch_bounds__(256) void k_cholinv(const double* __restrict__ Cin,
    float* __restrict__ Rinv)
{
  __shared__ double R[BSUB][BSUB + 1];   // 51.8 KB
  __shared__ double dinv[BSUB];
  __shared__ float X[BSUB][BSUB + 1];    // 25.9 KB
  int t = threadIdx.x;
  for (int idx = t; idx < BSUB * BSUB; idx += 256)
    R[idx / BSUB][idx % BSUB] = Cin[idx];
  __syncthreads();
  double flr0 = 1e-30 * (fabs(R[0][0]) + 1e-280);
  for (int k = 0; k < BSUB - 1; k++) {
    double piv = R[k][k];
    if (piv < flr0) piv = flr0;
    double rp = 1.0 / piv;
    int nrem = BSUB - 1 - k;
    int total = (nrem * (nrem + 1)) >> 1;
    for (int idx = t; idx < total; idx += 256) {
      float nf = 2.f * (float)nrem + 1.f;
      int a = (int)((nf - sqrtf(nf * nf - 8.f * (float)idx)) * 0.5f);
      while (a > 0 && a * nrem - ((a * (a - 1)) >> 1) > idx) a--;
      while ((a + 1) * nrem - (((a + 1) * a) >> 1) <= idx) a++;
      int off = idx - (a * nrem - ((a * (a - 1)) >> 1));
      int i2 = k + 1 + a, j2 = i2 + off;
      R[i2][j2] -= R[k][i2] * R[k][j2] * rp;
    }
    __syncthreads();
  }
  if (t < BSUB) {
    double piv = R[t][t];
    if (piv < flr0) piv = flr0;
    dinv[t] = 1.0 / sqrt(piv);
  }
  __syncthreads();
  for (int idx = t; idx < BSUB * BSUB; idx += 256) {
    int k = idx / BSUB, j = idx % BSUB;
    if (j > k) R[k][j] *= dinv[k];
  }
  __syncthreads();
  if (t < BSUB) R[t][t] = 1.0 / dinv[t];
  __syncthreads();
  if (t < BSUB) {
    int j = t;
    X[j][j] = (float)dinv[j];
    for (int i = j - 1; i >= 0; i--) {
      double s = 0.0;
      for (int k2 = i + 1; k2 <= j; k2++) s += R[i][k2] * (double)X[k2][j];
      X[i][j] = (float)(-s * dinv[i]);
    }
    for (int i = j + 1; i < BSUB; i++) X[i][j] = 0.f;
  }
  __syncthreads();
  for (int idx = t; idx < BSUB * BSUB; idx += 256)
    Rinv[idx] = X[idx / BSUB][idx % BSUB];
}

// out = S @ Rinv   (1024x80 * 80x80)
__global__ __launch_bounds__(256) void k_gemmSR(const float* __restrict__ S,
    const float* __restrict__ Rinv, float* __restrict__ out)
{
  __shared__ float Rsh[BSUB][84];
  int t = threadIdx.x;
  for (int idx = t; idx < BSUB * BSUB; idx += 256)
    Rsh[idx / BSUB][idx % BSUB] = Rinv[idx];
  __syncthreads();
  int r0 = blockIdx.x * 32;
  int r = t >> 3, c0 = (t & 7) * 10;
  float acc[10] = {};
  const float* srow = &S[(size_t)(r0 + r) * BSUB];
  for (int k = 0; k < BSUB; k++) {
    float s = srow[k];
    #pragma unroll
    for (int m = 0; m < 10; m++) acc[m] += s * Rsh[k][c0 + m];
  }
  #pragma unroll
  for (int m = 0; m < 10; m++) out[(size_t)(r0 + r) * BSUB + c0 + m] = acc[m];
}

// ---------------------------------------------------------------------------
// 80x80 symmetric Jacobi, single block, 512 threads, TWO barriers per round.
__global__ __launch_bounds__(512) void k_jacobi(const float* __restrict__ Min,
    float* __restrict__ Uout, int* __restrict__ perm,
    double* __restrict__ cutout, int sweeps, int withU)
{
  __shared__ float Mb[2][BSUB][BSUB + 1];   // 51.8 KB
  __shared__ float Ut[BSUB][BSUB];          // 25.6 KB, Ut[p][k] = U[k][p]
  __shared__ float cs[2][40], sn[2][40];
  __shared__ int pp[2][40], qq[2][40];
  __shared__ float colc[2][BSUB], cols[2][BSUB];
  __shared__ int cpart[2][BSUB];
  __shared__ float th[BSUB];
  __shared__ int id[BSUB];
  int t = threadIdx.x;
  for (int idx = t; idx < BSUB * BSUB; idx += 512) {
    int i2 = idx / BSUB, j2 = idx % BSUB;
    Mb[0][i2][j2] = 0.5f * (Min[i2 * BSUB + j2] + Min[j2 * BSUB + i2]);
    if (withU) Ut[i2][j2] = (i2 == j2) ? 1.f : 0.f;
  }
  __syncthreads();
  int nrounds = sweeps * (BSUB - 1);
  int mcur = 0;
  for (int it = 0; it < nrounds; it++) {
    int r = it % (BSUB - 1);
    int pb = it & 1;
    float (*Mc)[BSUB + 1] = Mb[mcur];
    float (*Mn)[BSUB + 1] = Mb[mcur ^ 1];
    if (t < 40) {
      int p = (t == 0) ? 0 : 1 + (t - 1 + r) % (BSUB - 1);
      int q = 1 + (BSUB - 2 - t + r) % (BSUB - 1);
      if (p > q) { int tmp = p; p = q; q = tmp; }
      pp[pb][t] = p; qq[pb][t] = q;
      float apq = Mc[p][q];
      float c = 1.f, s = 0.f;
      if (fabsf(apq) > 1e-28f) {
        float tau = (Mc[q][q] - Mc[p][p]) / (2.f * apq);
        float tt = copysignf(1.f, tau) / (fabsf(tau) + sqrtf(1.f + tau * tau));
        c = rsqrtf(1.f + tt * tt);
        s = tt * c;
      }
      cs[pb][t] = c; sn[pb][t] = s;
      colc[pb][p] = c; cols[pb][p] = s; cpart[pb][p] = q;
      colc[pb][q] = c; cols[pb][q] = s; cpart[pb][q] = p;
    } else if (withU && it > 0) {
      int ob = pb ^ 1;
      for (int idx = t - 40; idx < 40 * BSUB; idx += 472) {
        int pr = idx / BSUB, k = idx - pr * BSUB;
        int p = pp[ob][pr], q = qq[ob][pr];
        float c = cs[ob][pr], s = sn[ob][pr];
        float up = Ut[p][k], uq = Ut[q][k];
        Ut[p][k] = c * up - s * uq;
        Ut[q][k] = s * up + c * uq;
      }
    }
    __syncthreads();
    for (int idx = t; idx < 40 * BSUB; idx += 512) {
      int pr = idx / BSUB, k = idx - pr * BSUB;
      int p = pp[pb][pr], q = qq[pb][pr];
      float c = cs[pb][pr], s = sn[pb][pr];
      int k2 = cpart[pb][k];
      float ck = colc[pb][k], sk = cols[pb][k];
      float mpk = Mc[p][k],  mqk = Mc[q][k];
      float mpk2 = Mc[p][k2], mqk2 = Mc[q][k2];
      float rpk  = c * mpk  - s * mqk;
      float rqk  = s * mpk  + c * mqk;
      float rpk2 = c * mpk2 - s * mqk2;
      float rqk2 = s * mpk2 + c * mqk2;
      float npk, nqk;
      if (k < k2) {
        npk = ck * rpk - sk * rpk2;
        nqk = ck * rqk - sk * rqk2;
      } else {
        npk = sk * rpk2 + ck * rpk;
        nqk = sk * rqk2 + ck * rqk;
      }
      Mn[p][k] = npk;
      Mn[q][k] = nqk;
    }
    __syncthreads();
    mcur ^= 1;
  }
  if (withU) {
    int ob = (nrounds - 1) & 1;
    for (int idx = t; idx < 40 * BSUB; idx += 512) {
      int pr = idx / BSUB, k = idx - pr * BSUB;
      int p = pp[ob][pr], q = qq[ob][pr];
      float c = cs[ob][pr], s = sn[ob][pr];
      float up = Ut[p][k], uq = Ut[q][k];
      Ut[p][k] = c * up - s * uq;
      Ut[q][k] = s * up + c * uq;
    }
    __syncthreads();
  }
  float (*Mf)[BSUB + 1] = Mb[mcur];
  if (t < BSUB) { th[t] = Mf[t][t]; id[t] = t; }
  __syncthreads();
  if (t == 0) {
    for (int a = 1; a < BSUB; a++) {
      float v = th[a]; int ii = id[a]; int b = a - 1;
      while (b >= 0 && th[b] < v) { th[b + 1] = th[b]; id[b + 1] = id[b]; b--; }
      th[b + 1] = v; id[b + 1] = ii;
    }
    double cut = (double)th[BSUB - 1];
    double lo = 0.02 * (double)th[0];
    if (cut < lo) cut = lo;
    double hi = 0.98 * (double)th[63];
    if (cut > hi) cut = hi;
    cutout[0] = cut;
  }
  __syncthreads();
  if (t < BSUB) perm[t] = id[t];
  if (withU)
    for (int idx = t; idx < BSUB * BSUB; idx += 512) {
      int k = idx / BSUB, p = idx % BSUB;
      Uout[idx] = Ut[p][k];
    }
}

// out[:, c] = S @ U[:, perm[c]], c < 64
__global__ __launch_bounds__(256) void k_compose(const float* __restrict__ S,
    const float* __restrict__ U, const int* __restrict__ perm,
    float* __restrict__ out)
{
  __shared__ float Ush[BSUB][65];
  int t = threadIdx.x;
  for (int idx = t; idx < BSUB * 64; idx += 256) {
    int jj = idx >> 6, c = idx & 63;
    Ush[jj][c] = U[jj * BSUB + perm[c]];
  }
  __syncthreads();
  int r0 = blockIdx.x * 64;
  for (int oidx = t; oidx < 64 * 64; oidx += 256) {
    int r = oidx >> 6, c = oidx & 63;
    float acc = 0.f;
    const float* srow = &S[(size_t)(r0 + r) * BSUB];
    #pragma unroll 8
    for (int j = 0; j < BSUB; j++) acc += srow[j] * Ush[j][c];
    out[(size_t)(r0 + r) * 64 + c] = acc;
  }
}

// ---------------------------------------------------------------------------
// fused: proj[d] = (1/16) * neigh_d @ Vtop, then hout = relu(proj @ W^T + b)
__global__ __launch_bounds__(256) void k_projlin(const float* __restrict__ hl,
    const int* __restrict__ src, const float* __restrict__ Vtop,
    const float* __restrict__ W, const float* __restrict__ bias,
    float* __restrict__ hout)
{
  __shared__ float Vsh[64][68];
  __shared__ float Hsh[64][68];
  __shared__ float Psh[64][68];
  int t = threadIdx.x;
  int d0 = blockIdx.x * 64;
  int dd = t & 63, pg = t >> 6;
  float acc[16] = {};
  for (int k = 0; k < 16; k++) {
    __syncthreads();
    for (int item = t; item < 1024; item += 256) {
      int rr = item >> 4, f4 = item & 15;
      *(float4*)&Vsh[rr][f4 * 4] = ((const float4*)Vtop)[(size_t)(k * 64 + rr) * 16 + f4];
      int d = d0 + rr;
      float4 v = make_float4(0.f, 0.f, 0.f, 0.f);
      if (d < NNODES) {
        int row = (k < EPN) ? src[d * EPN + k] : d;
        v = ((const float4*)hl)[(size_t)row * 16 + f4];
      }
      *(float4*)&Hsh[rr][f4 * 4] = v;
    }
    __syncthreads();
    for (int j = 0; j < 64; j++) {
      float h = Hsh[dd][j];
      #pragma unroll
      for (int m = 0; m < 16; m++) acc[m] += h * Vsh[j][pg * 16 + m];
    }
  }
  __syncthreads();
  #pragma unroll
  for (int m = 0; m < 16; m++) Psh[dd][pg * 16 + m] = acc[m] * (1.f / 16.f);
  for (int item = t; item < 1024; item += 256) {
    int rr = item >> 4, f4 = item & 15;
    *(float4*)&Vsh[rr][f4 * 4] = ((const float4*)W)[(size_t)rr * 16 + f4];
  }
  __syncthreads();
  if (d0 + dd < NNODES) {
    #pragma unroll
    for (int m = 0; m < 16; m++) {
      int o = pg * 16 + m;
      float a = bias[o];
      for (int j = 0; j < 64; j++) a += Psh[dd][j] * Vsh[o][j];
      hout[(size_t)(d0 + dd) * 64 + o] = fmaxf(a, 0.f);
    }
  }
}

__global__ void k_logsoftmax(const float* __restrict__ logits, float* __restrict__ out)
{
  int n = blockIdx.x * 256 + threadIdx.x;
  if (n >= NNODES) return;
  float v[NCLS];
  float mx = -1e30f;
  #pragma unroll
  for (int c = 0; c < NCLS; c++) { v[c] = logits[(size_t)n * NCLS + c]; mx = fmaxf(mx, v[c]); }
  float se = 0.f;
  #pragma unroll
  for (int c = 0; c < NCLS; c++) se += expf(v[c] - mx);
  float lse = mx + logf(se);
  #pragma unroll
  for (int c = 0; c < NCLS; c++) out[(size_t)n * NCLS + c] = v[c] - lse;
}

// ===========================================================================
extern "C" void kernel_launch(void* const* d_in, const int* in_sizes, int n_in,
                              void* d_out, int out_size, void* d_ws, size_t ws_size,
                              hipStream_t stream)
{
  (void)in_sizes; (void)n_in; (void)out_size; (void)ws_size;
  const float* x = (const float*)d_in[0];
  const int* src = (const int*)d_in[1];
  const float* Wl[3] = { (const float*)d_in[2], (const float*)d_in[4], (const float*)d_in[6] };
  const float* bl[3] = { (const float*)d_in[3], (const float*)d_in[5], (const float*)d_in[7] };
  const float* Wfc = (const float*)d_in[8];
  const float* bfc = (const float*)d_in[9];
  float* outp = (float*)d_out;

  char* w = (char*)d_ws;
  auto alloc = [&](size_t bytes) -> char* {
    char* p = w; w += (bytes + 255) & ~(size_t)255; return p;
  };
  float* hA   = (float*)alloc((size_t)NNODES * 64 * 4);
  float* hB   = (float*)alloc((size_t)NNODES * 64 * 4);
  float* hl   = (float*)alloc((size_t)NNODES * 64 * 4);
  float* T    = (float*)alloc((size_t)NB * NB * 4);
  float* G    = (float*)alloc((size_t)NB * NB * 4);
  float* mus  = (float*)alloc(16 * 64 * 4);
  float* Zb[6];
  for (int i = 0; i < 6; i++) Zb[i] = (float*)alloc((size_t)NB * BSUB * 4);
  float* P     = (float*)alloc((size_t)8 * NB * BSUB * 4);
  int* cnt     = (int*)alloc(32 * 4);
  double* C    = (double*)alloc(BSUB * BSUB * 8);
  float* Rinv  = (float*)alloc(BSUB * BSUB * 4);
  float* Mm    = (float*)alloc(BSUB * BSUB * 4);
  float* U     = (float*)alloc(BSUB * BSUB * 4);
  int* perm    = (int*)alloc(BSUB * 4);
  float* Vtop  = (float*)alloc((size_t)NB * 64 * 4);
  double* scal = (double*)alloc(8 * 8);

  const int GRID_ROWS = (NNODES + 63) / 64;   // 313

  hipMemsetAsync(cnt, 0, 32 * 4, stream);     // combine counters (self-resetting)

  int cur = 0;
  auto gemmGZ = [&](const float* Z, const float* Zp, float* o,
                    const double* cptr, float s1, float s2, float s3) {
    hipLaunchKernelGGL(k_gzfused, dim3(32, 8), dim3(256), 0, stream,
                       G, Z, Zp, P, o, cnt, cptr, s1, s2, s3);
  };
  auto chunk = [&](int deg, double* cptr) {
    int a = (cur + 1) % 6, b = (cur + 2) % 6;
    float* z0 = Zb[cur];
    float* z1 = Zb[a];
    float* z2 = Zb[b];
    void* args[] = { (void*)&G, (void*)&z0, (void*)&z1, (void*)&z2,
                     (void*)&P, (void*)&cnt, (void*)&cptr, (void*)&deg };
    hipLaunchCooperativeKernel((const void*)k_chebchunk, dim3(32, 8), dim3(256),
                               args, 0, stream);
    // result buffer: [1,2,0][(deg-1)%3] of {z0,z1,z2}
    int sel = ((deg - 1) % 3);
    cur = (sel == 0) ? a : (sel == 1) ? b : cur;
  };
  auto cholqr = [&]() {
    hipLaunchKernelGGL(k_syrk, dim3(25), dim3(256), 0, stream, Zb[cur], C);
    hipLaunchKernelGGL(k_cholinv, dim3(1), dim3(256), 0, stream, C, Rinv);
    int o = (cur + 1) % 6;
    hipLaunchKernelGGL(k_gemmSR, dim3(32), dim3(256), 0, stream, Zb[cur], Rinv, Zb[o]);
    cur = o;
  };
  auto rrmid = [&](double* cutp) {
    int y = (cur + 1) % 6;
    gemmGZ(Zb[cur], nullptr, Zb[y], nullptr, 1.f, 0.f, 0.f);   // Y = G S
    hipLaunchKernelGGL(k_xty, dim3(25), dim3(256), 0, stream, Zb[cur], Zb[y], Mm);
    hipLaunchKernelGGL(k_jacobi, dim3(1), dim3(512), 0, stream,
                       Mm, U, perm, cutp, 2, 0);
  };
  auto rrfinal = [&](double* cutp) {
    int y = (cur + 1) % 6;
    gemmGZ(Zb[cur], nullptr, Zb[y], nullptr, 1.f, 0.f, 0.f);   // Y = G S
    hipLaunchKernelGGL(k_xty, dim3(25), dim3(256), 0, stream, Zb[cur], Zb[y], Mm);
    hipLaunchKernelGGL(k_jacobi, dim3(1), dim3(512), 0, stream,
                       Mm, U, perm, cutp, 5, 1);
    hipLaunchKernelGGL(k_compose, dim3(16), dim3(256), 0, stream,
                       Zb[cur], U, perm, Vtop);
  };

  const float* hin = x;
  float* hout = hA;
  for (int l = 0; l < 3; l++) {
    hipLaunchKernelGGL(k_linT, dim3(GRID_ROWS), dim3(256), 0, stream,
                       hin, Wl[l], (const float*)nullptr, hl, 64, 0);
    hipMemsetAsync(mus, 0, 16 * 64 * 4, stream);
    hipLaunchKernelGGL(k_meanslot, dim3(16, 8), dim3(256), 0, stream, hl, src, mus);
    hipMemsetAsync(T, 0, (size_t)NB * NB * 4, stream);
    hipLaunchKernelGGL(k_gram, dim3(136, 5), dim3(256), 0, stream, hl, src, mus, T);
    hipLaunchKernelGGL(k_assembleG, dim3(4096), dim3(256), 0, stream, T, G);
    hipLaunchKernelGGL(k_cut0, dim3(1), dim3(256), 0, stream, G, scal);
    cur = 0;
    hipLaunchKernelGGL(k_initS, dim3((NB * BSUB + 255) / 256), dim3(256), 0, stream, Zb[cur]);
    chunk(10, &scal[0]); cholqr();
    rrmid(&scal[1]);
    chunk(13, &scal[1]); cholqr();
    chunk(13, &scal[1]); cholqr();
    rrfinal(&scal[2]);
    hipLaunchKernelGGL(k_projlin, dim3(GRID_ROWS), dim3(256), 0, stream,
                       hl, src, Vtop, Wl[l], bl[l], hout);
    hin = hout;
    hout = (hout == hA) ? hB : hA;
  }
  hipLaunchKernelGGL(k_linT, dim3(GRID_ROWS), dim3(256), 0, stream,
                     hin, Wfc, bfc, hl, NCLS, 0);
  hipLaunchKernelGGL(k_logsoftmax, dim3((NNODES + 255) / 256), dim3(256), 0, stream,
                     hl, outp);
}

// Round 9
// 12344.973 us; speedup vs baseline: 1.4300x; 1.4300x over previous
//
#include <hip/hip_runtime.h>
#include <cmath>

#define NNODES 20000
#define FD 64
#define EPN 15      // regular edges per node
#define NB 1024     // DEG * F
#define BSUB 80     // subspace width (top-64 + 16 buffer)
#define NCLS 16

// ---------------------------------------------------------------------------
// out[n][o] = relu?( sum_j X[n][j] * W[o][j] + bias[o] ), X: [N,64], W: [ncol,64]
__global__ __launch_bounds__(256) void k_linT(const float* __restrict__ X,
    const float* __restrict__ W, const float* __restrict__ bias,
    float* __restrict__ out, int ncol, int relu)
{
  __shared__ float Wsh[64][65];
  __shared__ float Xsh[64][65];
  int t = threadIdx.x;
  int r0 = blockIdx.x * 64;
  for (int idx = t; idx < ncol * 64; idx += 256) Wsh[idx >> 6][idx & 63] = W[idx];
  for (int idx = t; idx < 64 * 64; idx += 256) {
    int r = idx >> 6, c = idx & 63;
    Xsh[r][c] = (r0 + r < NNODES) ? X[(size_t)(r0 + r) * 64 + c] : 0.f;
  }
  __syncthreads();
  for (int idx = t; idx < 64 * ncol; idx += 256) {
    int r = idx / ncol, o = idx % ncol;
    float acc = 0.f;
    #pragma unroll
    for (int j = 0; j < 64; j++) acc += Xsh[r][j] * Wsh[o][j];
    if (bias) acc += bias[o];
    if (relu) acc = fmaxf(acc, 0.f);
    if (r0 + r < NNODES) out[(size_t)(r0 + r) * ncol + o] = acc;
  }
}

// ---------------------------------------------------------------------------
__global__ __launch_bounds__(256) void k_meanslot(const float* __restrict__ hl,
    const int* __restrict__ src, float* __restrict__ mus)
{
  int k = blockIdx.x;          // slot 0..15
  int part = blockIdx.y;       // 8 parts x 2500 nodes
  int t = threadIdx.x;
  int c = t & 63, sub = t >> 6;
  int d0 = part * 2500;
  float acc = 0.f;
  for (int d = d0 + sub; d < d0 + 2500; d += 4) {
    int row = (k < EPN) ? src[d * EPN + k] : d;
    acc += hl[(size_t)row * 64 + c];
  }
  __shared__ float red[4][64];
  red[sub][c] = acc;
  __syncthreads();
  if (t < 64) {
    float s = red[0][t] + red[1][t] + red[2][t] + red[3][t];
    atomicAdd(&mus[k * 64 + t], s * (1.f / 20000.f));
  }
}

// ---------------------------------------------------------------------------
__global__ __launch_bounds__(256) void k_gram(const float* __restrict__ hl,
    const int* __restrict__ src, const float* __restrict__ mus,
    float* __restrict__ T)
{
  __shared__ float Ash[64][64];
  __shared__ float Bsh[64][64];
  __shared__ float muA[64], muB[64];
  int t = threadIdx.x;
  int pr = blockIdx.x, i = 0, rem = pr;
  for (int ii = 0; ii < 16; ii++) {
    int cnt = 16 - ii;
    if (rem < cnt) { i = ii; break; }
    rem -= cnt;
  }
  int j = i + rem;
  if (t < 64) muA[t] = mus[i * 64 + t];
  else if (t < 128) muB[t - 64] = mus[j * 64 + (t - 64)];
  float acc[4][4] = {};
  int a0 = (t & 15) * 4, b0 = (t >> 4) * 4;
  int d0 = blockIdx.y * 4000, d1 = d0 + 4000;
  for (int dc = d0; dc < d1; dc += 64) {
    __syncthreads();
    for (int item = t; item < 1024; item += 256) {
      int rr = item >> 4, f4 = item & 15;
      int d = dc + rr;
      float4 va = make_float4(0.f, 0.f, 0.f, 0.f);
      float4 vb = va;
      if (d < d1) {
        int ra = (i < EPN) ? src[d * EPN + i] : d;
        int rb = (j < EPN) ? src[d * EPN + j] : d;
        va = ((const float4*)hl)[(size_t)ra * 16 + f4];
        vb = ((const float4*)hl)[(size_t)rb * 16 + f4];
        int cb = f4 * 4;
        va.x -= muA[cb]; va.y -= muA[cb + 1]; va.z -= muA[cb + 2]; va.w -= muA[cb + 3];
        vb.x -= muB[cb]; vb.y -= muB[cb + 1]; vb.z -= muB[cb + 2]; vb.w -= muB[cb + 3];
      }
      ((float4*)&Ash[rr][0])[f4] = va;
      ((float4*)&Bsh[rr][0])[f4] = vb;
    }
    __syncthreads();
    for (int dd = 0; dd < 64; dd++) {
      float av[4], bv[4];
      #pragma unroll
      for (int u = 0; u < 4; u++) av[u] = Ash[dd][a0 + u];
      #pragma unroll
      for (int u = 0; u < 4; u++) bv[u] = Bsh[dd][b0 + u];
      #pragma unroll
      for (int x = 0; x < 4; x++)
        #pragma unroll
        for (int y = 0; y < 4; y++) acc[x][y] += av[x] * bv[y];
    }
  }
  #pragma unroll
  for (int x = 0; x < 4; x++)
    #pragma unroll
    for (int y = 0; y < 4; y++)
      atomicAdd(&T[(size_t)(i * 64 + a0 + x) * NB + (j * 64 + b0 + y)], acc[x][y]);
}

// ---------------------------------------------------------------------------
__global__ __launch_bounds__(256) void k_assembleG(const float* __restrict__ T,
    float* __restrict__ G)
{
  size_t idx = (size_t)blockIdx.x * 256 + threadIdx.x;
  int p = (int)(idx >> 10), q = (int)(idx & 1023);
  int ti = p >> 6, tj = q >> 6;
  float v = (ti <= tj) ? T[idx] : T[((size_t)q << 10) | (size_t)p];
  G[idx] = v * (1.f / 256.f);
}

__global__ void k_cut0(const float* __restrict__ G, double* __restrict__ scal)
{
  __shared__ float red[256];
  float m = 0.f;
  for (int p = threadIdx.x; p < NB; p += 256) m = fmaxf(m, G[(size_t)p * NB + p]);
  red[threadIdx.x] = m;
  __syncthreads();
  for (int s = 128; s; s >>= 1) {
    if (threadIdx.x < s) red[threadIdx.x] = fmaxf(red[threadIdx.x], red[threadIdx.x + s]);
    __syncthreads();
  }
  if (threadIdx.x == 0) scal[0] = 0.9 * (double)red[0];
}

__global__ void k_initS(float* __restrict__ S)
{
  int idx = blockIdx.x * 256 + threadIdx.x;
  if (idx < NB * BSUB) {
    unsigned u = (unsigned)(idx + 1) * 2654435761u;
    u ^= u >> 16; u *= 2246822519u; u ^= u >> 13; u *= 3266489917u; u ^= u >> 16;
    S[idx] = ((float)u * (1.f / 4294967296.f)) - 0.5f;
  }
}

// ---------------------------------------------------------------------------
// Fused G@Z with split-K + in-kernel combine (fire-and-forget).
__global__ __launch_bounds__(256) void k_gzfused(const float* __restrict__ G,
    const float* __restrict__ Z, const float* __restrict__ Zp,
    float* __restrict__ P, float* __restrict__ out, int* __restrict__ cnt,
    const double* __restrict__ cptr, float s1, float s2, float s3)
{
  __shared__ float Gs[32][68];
  __shared__ float Zs[64][84];
  __shared__ int lastf;
  int t = threadIdx.x;
  int r0b = blockIdx.x;
  int r0 = r0b * 32;
  int kz = blockIdx.y;
  int cg = t & 15, rg = t >> 4;
  float acc0[5] = {}, acc1[5] = {};
  for (int k0 = kz * 128; k0 < kz * 128 + 128; k0 += 64) {
    __syncthreads();
    #pragma unroll
    for (int s = 0; s < 2; s++) {
      int item = t + s * 256;
      int rr = item >> 4, f4 = item & 15;
      float4 g = ((const float4*)G)[(size_t)(r0 + rr) * 256 + (k0 >> 2) + f4];
      *(float4*)&Gs[rr][f4 * 4] = g;
    }
    #pragma unroll
    for (int s = 0; s < 5; s++) {
      int item = t + s * 256;
      int rr = item / 20, f4 = item % 20;
      float4 z = ((const float4*)Z)[(size_t)(k0 + rr) * 20 + f4];
      *(float4*)&Zs[rr][f4 * 4] = z;
    }
    __syncthreads();
    for (int kk = 0; kk < 64; kk++) {
      float g0 = Gs[rg * 2 + 0][kk];
      float g1 = Gs[rg * 2 + 1][kk];
      float z[5];
      #pragma unroll
      for (int m = 0; m < 5; m++) z[m] = Zs[kk][cg * 5 + m];
      #pragma unroll
      for (int m = 0; m < 5; m++) { acc0[m] += g0 * z[m]; acc1[m] += g1 * z[m]; }
    }
  }
  size_t base = (size_t)kz * (NB * BSUB) + (size_t)(r0 + rg * 2) * BSUB + cg * 5;
  #pragma unroll
  for (int m = 0; m < 5; m++) P[base + m] = acc0[m];
  #pragma unroll
  for (int m = 0; m < 5; m++) P[base + BSUB + m] = acc1[m];
  __threadfence();
  __syncthreads();
  if (t == 0) {
    int old = atomicAdd(&cnt[r0b], 1);
    lastf = (old == 7) ? 1 : 0;
  }
  __syncthreads();
  if (!lastf) return;
  __threadfence();
  float coef = s1;
  if (cptr) coef = s1 * (float)(2.0 / cptr[0]);
  const float4* P4 = (const float4*)P;
  for (int idx = t; idx < 640; idx += 256) {
    size_t o4 = (size_t)r0 * 20 + idx;
    float4 a = P4[o4];
    #pragma unroll
    for (int u = 1; u < 8; u++) {
      float4 b = P4[(size_t)u * 20480 + o4];
      a.x += b.x; a.y += b.y; a.z += b.z; a.w += b.w;
    }
    float4 z = ((const float4*)Z)[o4];
    float4 o;
    o.x = coef * a.x + s2 * z.x;
    o.y = coef * a.y + s2 * z.y;
    o.z = coef * a.z + s2 * z.z;
    o.w = coef * a.w + s2 * z.w;
    if (s3 != 0.f) {
      float4 zp = ((const float4*)Zp)[o4];
      o.x += s3 * zp.x; o.y += s3 * zp.y; o.z += s3 * zp.z; o.w += s3 * zp.w;
    }
    ((float4*)out)[o4] = o;
  }
  __syncthreads();
  if (t == 0) cnt[r0b] = 0;
}

// C (f64) = S^T S
__global__ void k_syrk(const float* __restrict__ S, double* __restrict__ C)
{
  int idx = blockIdx.x * 256 + threadIdx.x;
  if (idx >= BSUB * BSUB) return;
  int a = idx / BSUB, b = idx % BSUB;
  double acc = 0.0;
  for (int i = 0; i < NB; i++)
    acc += (double)S[(size_t)i * BSUB + a] * (double)S[(size_t)i * BSUB + b];
  C[idx] = acc;
}

// M (f32, f64 accum) = X^T Y
__global__ void k_xty(const float* __restrict__ X, const float* __restrict__ Y,
                      float* __restrict__ M)
{
  int idx = blockIdx.x * 256 + threadIdx.x;
  if (idx >= BSUB * BSUB) return;
  int a = idx / BSUB, b = idx % BSUB;
  double acc = 0.0;
  for (int i = 0; i < NB; i++)
    acc += (double)X[(size_t)i * BSUB + a] * (double)Y[(size_t)i * BSUB + b];
  M[idx] = (float)acc;
}

// ---------------------------------------------------------------------------
// fused Cholesky (f64, LDS) + triangular inverse -> Rinv (f32).
// TWO pivot columns eliminated per barrier: for trailing i >= k+2 the (k+1)
// update is computed in-register from pre-update values; row k+1's new values
// go to a double-buffered scratch row and are copied back next phase (that
// phase never reads row k+1). Same arithmetic expressions as single-column.
__global__ __launch_bounds__(512) void k_cholinv(const double* __restrict__ Cin,
    float* __restrict__ Rinv)
{
  __shared__ double R[BSUB][BSUB + 1];   // 51.8 KB
  __shared__ double rownew[2][BSUB];
  __shared__ double dinv[BSUB];
  __shared__ float X[BSUB][BSUB + 1];    // 25.9 KB
  int t = threadIdx.x;
  for (int idx = t; idx < BSUB * BSUB; idx += 512)
    R[idx / BSUB][idx % BSUB] = Cin[idx];
  __syncthreads();
  double flr0 = 1e-30 * (fabs(R[0][0]) + 1e-280);
  int prevrow = -1;
  int pb = 0;
  int k = 0;
  while (k < BSUB - 1) {
    int nrem = BSUB - 1 - k;                  // rows k+1..BSUB-1
    int total = (nrem * (nrem + 1)) >> 1;
    int cplen = (prevrow >= 0) ? (BSUB - prevrow) : 0;
    double piv = R[k][k];
    if (piv < flr0) piv = flr0;
    double rp = 1.0 / piv;
    bool pair = (k + 1 < BSUB - 1);
    if (pair) {
      double dk1 = R[k][k + 1];
      double p1 = R[k + 1][k + 1] - dk1 * dk1 * rp;
      if (p1 < flr0) p1 = flr0;
      double rp1 = 1.0 / p1;
      for (int idx = t; idx < total + cplen; idx += 512) {
        if (idx < total) {
          float nf = 2.f * (float)nrem + 1.f;
          int a = (int)((nf - sqrtf(nf * nf - 8.f * (float)idx)) * 0.5f);
          while (a > 0 && a * nrem - ((a * (a - 1)) >> 1) > idx) a--;
          while ((a + 1) * nrem - (((a + 1) * a) >> 1) <= idx) a++;
          int off = idx - (a * nrem - ((a * (a - 1)) >> 1));
          int i2 = k + 1 + a, j2 = i2 + off;
          if (a == 0) {
            rownew[pb][j2] = R[k + 1][j2] - dk1 * R[k][j2] * rp;
          } else {
            double v = R[i2][j2] - R[k][i2] * R[k][j2] * rp;
            double R1i = R[k + 1][i2] - dk1 * R[k][i2] * rp;
            double R1j = R[k + 1][j2] - dk1 * R[k][j2] * rp;
            v -= R1i * R1j * rp1;
            R[i2][j2] = v;
          }
        } else {
          int j = prevrow + (idx - total);
          R[prevrow][j] = rownew[pb ^ 1][j];
        }
      }
      __syncthreads();
      prevrow = k + 1; pb ^= 1; k += 2;
    } else {
      // single trailing column
      for (int idx = t; idx < total + cplen; idx += 512) {
        if (idx < total) {
          float nf = 2.f * (float)nrem + 1.f;
          int a = (int)((nf - sqrtf(nf * nf - 8.f * (float)idx)) * 0.5f);
          while (a > 0 && a * nrem - ((a * (a - 1)) >> 1) > idx) a--;
          while ((a + 1) * nrem - (((a + 1) * a) >> 1) <= idx) a++;
          int off = idx - (a * nrem - ((a * (a - 1)) >> 1));
          int i2 = k + 1 + a, j2 = i2 + off;
          R[i2][j2] -= R[k][i2] * R[k][j2] * rp;
        } else {
          int j = prevrow + (idx - total);
          R[prevrow][j] = rownew[pb ^ 1][j];
        }
      }
      __syncthreads();
      prevrow = -1; k += 1;
    }
  }
  if (prevrow >= 0) {   // defensive drain
    for (int j = prevrow + t; j < BSUB; j += 512) R[prevrow][j] = rownew[pb ^ 1][j];
    __syncthreads();
  }
  if (t < BSUB) {
    double piv = R[t][t];
    if (piv < flr0) piv = flr0;
    dinv[t] = 1.0 / sqrt(piv);
  }
  __syncthreads();
  for (int idx = t; idx < BSUB * BSUB; idx += 512) {
    int kk = idx / BSUB, j = idx % BSUB;
    if (j > kk) R[kk][j] *= dinv[kk];
  }
  __syncthreads();
  if (t < BSUB) R[t][t] = 1.0 / dinv[t];
  __syncthreads();
  if (t < BSUB) {
    int j = t;
    X[j][j] = (float)dinv[j];
    for (int i = j - 1; i >= 0; i--) {
      double s = 0.0;
      for (int k2 = i + 1; k2 <= j; k2++) s += R[i][k2] * (double)X[k2][j];
      X[i][j] = (float)(-s * dinv[i]);
    }
    for (int i = j + 1; i < BSUB; i++) X[i][j] = 0.f;
  }
  __syncthreads();
  for (int idx = t; idx < BSUB * BSUB; idx += 512)
    Rinv[idx] = X[idx / BSUB][idx % BSUB];
}

// out = S @ Rinv   (1024x80 * 80x80)
__global__ __launch_bounds__(256) void k_gemmSR(const float* __restrict__ S,
    const float* __restrict__ Rinv, float* __restrict__ out)
{
  __shared__ float Rsh[BSUB][84];
  int t = threadIdx.x;
  for (int idx = t; idx < BSUB * BSUB; idx += 256)
    Rsh[idx / BSUB][idx % BSUB] = Rinv[idx];
  __syncthreads();
  int r0 = blockIdx.x * 32;
  int r = t >> 3, c0 = (t & 7) * 10;
  float acc[10] = {};
  const float* srow = &S[(size_t)(r0 + r) * BSUB];
  for (int k = 0; k < BSUB; k++) {
    float s = srow[k];
    #pragma unroll
    for (int m = 0; m < 10; m++) acc[m] += s * Rsh[k][c0 + m];
  }
  #pragma unroll
  for (int m = 0; m < 10; m++) out[(size_t)(r0 + r) * BSUB + c0 + m] = acc[m];
}

// ---------------------------------------------------------------------------
// 80x80 symmetric Jacobi, single block, 1024 threads, TWO barriers per round.
// Phase A: 40 threads compute rotation params + per-column tables; remaining
// threads apply Ut rotations of round it-1 (double-buffered). Phase B:
// out-of-place row+col rotation, coalesced columns.
__global__ __launch_bounds__(1024) void k_jacobi(const float* __restrict__ Min,
    float* __restrict__ Uout, int* __restrict__ perm,
    double* __restrict__ cutout, int sweeps, int withU)
{
  __shared__ float Mb[2][BSUB][BSUB + 1];   // 51.8 KB
  __shared__ float Ut[BSUB][BSUB];          // 25.6 KB, Ut[p][k] = U[k][p]
  __shared__ float cs[2][40], sn[2][40];
  __shared__ int pp[2][40], qq[2][40];
  __shared__ float colc[2][BSUB], cols[2][BSUB];
  __shared__ int cpart[2][BSUB];
  __shared__ float th[BSUB];
  __shared__ int id[BSUB];
  int t = threadIdx.x;
  for (int idx = t; idx < BSUB * BSUB; idx += 1024) {
    int i2 = idx / BSUB, j2 = idx % BSUB;
    Mb[0][i2][j2] = 0.5f * (Min[i2 * BSUB + j2] + Min[j2 * BSUB + i2]);
    if (withU) Ut[i2][j2] = (i2 == j2) ? 1.f : 0.f;
  }
  __syncthreads();
  int nrounds = sweeps * (BSUB - 1);
  int mcur = 0;
  for (int it = 0; it < nrounds; it++) {
    int r = it % (BSUB - 1);
    int pb = it & 1;
    float (*Mc)[BSUB + 1] = Mb[mcur];
    float (*Mn)[BSUB + 1] = Mb[mcur ^ 1];
    if (t < 40) {
      int p = (t == 0) ? 0 : 1 + (t - 1 + r) % (BSUB - 1);
      int q = 1 + (BSUB - 2 - t + r) % (BSUB - 1);
      if (p > q) { int tmp = p; p = q; q = tmp; }
      pp[pb][t] = p; qq[pb][t] = q;
      float apq = Mc[p][q];
      float c = 1.f, s = 0.f;
      if (fabsf(apq) > 1e-28f) {
        float tau = (Mc[q][q] - Mc[p][p]) / (2.f * apq);
        float tt = copysignf(1.f, tau) / (fabsf(tau) + sqrtf(1.f + tau * tau));
        c = rsqrtf(1.f + tt * tt);
        s = tt * c;
      }
      cs[pb][t] = c; sn[pb][t] = s;
      colc[pb][p] = c; cols[pb][p] = s; cpart[pb][p] = q;
      colc[pb][q] = c; cols[pb][q] = s; cpart[pb][q] = p;
    } else if (withU && it > 0) {
      int ob = pb ^ 1;
      for (int idx = t - 40; idx < 40 * BSUB; idx += 984) {
        int pr = idx / BSUB, k = idx - pr * BSUB;
        int p = pp[ob][pr], q = qq[ob][pr];
        float c = cs[ob][pr], s = sn[ob][pr];
        float up = Ut[p][k], uq = Ut[q][k];
        Ut[p][k] = c * up - s * uq;
        Ut[q][k] = s * up + c * uq;
      }
    }
    __syncthreads();
    for (int idx = t; idx < 40 * BSUB; idx += 1024) {
      int pr = idx / BSUB, k = idx - pr * BSUB;
      int p = pp[pb][pr], q = qq[pb][pr];
      float c = cs[pb][pr], s = sn[pb][pr];
      int k2 = cpart[pb][k];
      float ck = colc[pb][k], sk = cols[pb][k];
      float mpk = Mc[p][k],  mqk = Mc[q][k];
      float mpk2 = Mc[p][k2], mqk2 = Mc[q][k2];
      float rpk  = c * mpk  - s * mqk;
      float rqk  = s * mpk  + c * mqk;
      float rpk2 = c * mpk2 - s * mqk2;
      float rqk2 = s * mpk2 + c * mqk2;
      float npk, nqk;
      if (k < k2) {
        npk = ck * rpk - sk * rpk2;
        nqk = ck * rqk - sk * rqk2;
      } else {
        npk = sk * rpk2 + ck * rpk;
        nqk = sk * rqk2 + ck * rqk;
      }
      Mn[p][k] = npk;
      Mn[q][k] = nqk;
    }
    __syncthreads();
    mcur ^= 1;
  }
  if (withU) {
    int ob = (nrounds - 1) & 1;
    for (int idx = t; idx < 40 * BSUB; idx += 1024) {
      int pr = idx / BSUB, k = idx - pr * BSUB;
      int p = pp[ob][pr], q = qq[ob][pr];
      float c = cs[ob][pr], s = sn[ob][pr];
      float up = Ut[p][k], uq = Ut[q][k];
      Ut[p][k] = c * up - s * uq;
      Ut[q][k] = s * up + c * uq;
    }
    __syncthreads();
  }
  float (*Mf)[BSUB + 1] = Mb[mcur];
  if (t < BSUB) { th[t] = Mf[t][t]; id[t] = t; }
  __syncthreads();
  if (t == 0) {
    for (int a = 1; a < BSUB; a++) {
      float v = th[a]; int ii = id[a]; int b = a - 1;
      while (b >= 0 && th[b] < v) { th[b + 1] = th[b]; id[b + 1] = id[b]; b--; }
      th[b + 1] = v; id[b + 1] = ii;
    }
    double cut = (double)th[BSUB - 1];
    double lo = 0.02 * (double)th[0];
    if (cut < lo) cut = lo;
    double hi = 0.98 * (double)th[63];
    if (cut > hi) cut = hi;
    cutout[0] = cut;
  }
  __syncthreads();
  if (t < BSUB) perm[t] = id[t];
  if (withU)
    for (int idx = t; idx < BSUB * BSUB; idx += 1024) {
      int k = idx / BSUB, p = idx % BSUB;
      Uout[idx] = Ut[p][k];
    }
}

// out[:, c] = S @ U[:, perm[c]], c < 64
__global__ __launch_bounds__(256) void k_compose(const float* __restrict__ S,
    const float* __restrict__ U, const int* __restrict__ perm,
    float* __restrict__ out)
{
  __shared__ float Ush[BSUB][65];
  int t = threadIdx.x;
  for (int idx = t; idx < BSUB * 64; idx += 256) {
    int jj = idx >> 6, c = idx & 63;
    Ush[jj][c] = U[jj * BSUB + perm[c]];
  }
  __syncthreads();
  int r0 = blockIdx.x * 64;
  for (int oidx = t; oidx < 64 * 64; oidx += 256) {
    int r = oidx >> 6, c = oidx & 63;
    float acc = 0.f;
    const float* srow = &S[(size_t)(r0 + r) * BSUB];
    #pragma unroll 8
    for (int j = 0; j < BSUB; j++) acc += srow[j] * Ush[j][c];
    out[(size_t)(r0 + r) * 64 + c] = acc;
  }
}

// ---------------------------------------------------------------------------
// fused: proj[d] = (1/16) * neigh_d @ Vtop, then hout = relu(proj @ W^T + b)
__global__ __launch_bounds__(256) void k_projlin(const float* __restrict__ hl,
    const int* __restrict__ src, const float* __restrict__ Vtop,
    const float* __restrict__ W, const float* __restrict__ bias,
    float* __restrict__ hout)
{
  __shared__ float Vsh[64][68];
  __shared__ float Hsh[64][68];
  __shared__ float Psh[64][68];
  int t = threadIdx.x;
  int d0 = blockIdx.x * 64;
  int dd = t & 63, pg = t >> 6;
  float acc[16] = {};
  for (int k = 0; k < 16; k++) {
    __syncthreads();
    for (int item = t; item < 1024; item += 256) {
      int rr = item >> 4, f4 = item & 15;
      *(float4*)&Vsh[rr][f4 * 4] = ((const float4*)Vtop)[(size_t)(k * 64 + rr) * 16 + f4];
      int d = d0 + rr;
      float4 v = make_float4(0.f, 0.f, 0.f, 0.f);
      if (d < NNODES) {
        int row = (k < EPN) ? src[d * EPN + k] : d;
        v = ((const float4*)hl)[(size_t)row * 16 + f4];
      }
      *(float4*)&Hsh[rr][f4 * 4] = v;
    }
    __syncthreads();
    for (int j = 0; j < 64; j++) {
      float h = Hsh[dd][j];
      #pragma unroll
      for (int m = 0; m < 16; m++) acc[m] += h * Vsh[j][pg * 16 + m];
    }
  }
  __syncthreads();
  #pragma unroll
  for (int m = 0; m < 16; m++) Psh[dd][pg * 16 + m] = acc[m] * (1.f / 16.f);
  for (int item = t; item < 1024; item += 256) {
    int rr = item >> 4, f4 = item & 15;
    *(float4*)&Vsh[rr][f4 * 4] = ((const float4*)W)[(size_t)rr * 16 + f4];
  }
  __syncthreads();
  if (d0 + dd < NNODES) {
    #pragma unroll
    for (int m = 0; m < 16; m++) {
      int o = pg * 16 + m;
      float a = bias[o];
      for (int j = 0; j < 64; j++) a += Psh[dd][j] * Vsh[o][j];
      hout[(size_t)(d0 + dd) * 64 + o] = fmaxf(a, 0.f);
    }
  }
}

__global__ void k_logsoftmax(const float* __restrict__ logits, float* __restrict__ out)
{
  int n = blockIdx.x * 256 + threadIdx.x;
  if (n >= NNODES) return;
  float v[NCLS];
  float mx = -1e30f;
  #pragma unroll
  for (int c = 0; c < NCLS; c++) { v[c] = logits[(size_t)n * NCLS + c]; mx = fmaxf(mx, v[c]); }
  float se = 0.f;
  #pragma unroll
  for (int c = 0; c < NCLS; c++) se += expf(v[c] - mx);
  float lse = mx + logf(se);
  #pragma unroll
  for (int c = 0; c < NCLS; c++) out[(size_t)n * NCLS + c] = v[c] - lse;
}

// ===========================================================================
extern "C" void kernel_launch(void* const* d_in, const int* in_sizes, int n_in,
                              void* d_out, int out_size, void* d_ws, size_t ws_size,
                              hipStream_t stream)
{
  (void)in_sizes; (void)n_in; (void)out_size; (void)ws_size;
  const float* x = (const float*)d_in[0];
  const int* src = (const int*)d_in[1];
  const float* Wl[3] = { (const float*)d_in[2], (const float*)d_in[4], (const float*)d_in[6] };
  const float* bl[3] = { (const float*)d_in[3], (const float*)d_in[5], (const float*)d_in[7] };
  const float* Wfc = (const float*)d_in[8];
  const float* bfc = (const float*)d_in[9];
  float* outp = (float*)d_out;

  char* w = (char*)d_ws;
  auto alloc = [&](size_t bytes) -> char* {
    char* p = w; w += (bytes + 255) & ~(size_t)255; return p;
  };
  float* hA   = (float*)alloc((size_t)NNODES * 64 * 4);
  float* hB   = (float*)alloc((size_t)NNODES * 64 * 4);
  float* hl   = (float*)alloc((size_t)NNODES * 64 * 4);
  float* T    = (float*)alloc((size_t)NB * NB * 4);
  float* G    = (float*)alloc((size_t)NB * NB * 4);
  float* mus  = (float*)alloc(16 * 64 * 4);
  float* Zb[6];
  for (int i = 0; i < 6; i++) Zb[i] = (float*)alloc((size_t)NB * BSUB * 4);
  float* P     = (float*)alloc((size_t)8 * NB * BSUB * 4);
  int* cnt     = (int*)alloc(32 * 4);
  double* C    = (double*)alloc(BSUB * BSUB * 8);
  float* Rinv  = (float*)alloc(BSUB * BSUB * 4);
  float* Mm    = (float*)alloc(BSUB * BSUB * 4);
  float* U     = (float*)alloc(BSUB * BSUB * 4);
  int* perm    = (int*)alloc(BSUB * 4);
  float* Vtop  = (float*)alloc((size_t)NB * 64 * 4);
  double* scal = (double*)alloc(8 * 8);

  const int GRID_ROWS = (NNODES + 63) / 64;   // 313

  hipMemsetAsync(cnt, 0, 32 * 4, stream);     // combine counters (self-resetting)

  int cur = 0;
  auto gemmGZ = [&](const float* Z, const float* Zp, float* o,
                    const double* cptr, float s1, float s2, float s3) {
    hipLaunchKernelGGL(k_gzfused, dim3(32, 8), dim3(256), 0, stream,
                       G, Z, Zp, P, o, cnt, cptr, s1, s2, s3);
  };
  // Chebyshev chunk as a chain of k_gzfused launches (3-buffer rotation,
  // identical coefficient sequence to R7).
  auto chunk = [&](int deg, const double* cptr) {
    int a = (cur + 1) % 6, b = (cur + 2) % 6;
    float* bufs[3] = { Zb[cur], Zb[a], Zb[b] };
    int ip = 0, ic = 0, io = 1;
    for (int s = 0; s < deg; s++) {
      if (s == 0)
        gemmGZ(bufs[ic], nullptr, bufs[io], cptr, 1.f, -1.f, 0.f);
      else
        gemmGZ(bufs[ic], bufs[ip], bufs[io], cptr, 2.f, -2.f, -1.f);
      if (s == 0) { ip = 0; ic = 1; io = 2; }
      else { int tmp = ip; ip = ic; ic = io; io = tmp; }
    }
    int sel = (deg - 1) % 3;   // final buffer: [1,2,0][sel] of {cur,a,b}
    cur = (sel == 0) ? a : (sel == 1) ? b : cur;
  };
  auto cholqr = [&]() {
    hipLaunchKernelGGL(k_syrk, dim3(25), dim3(256), 0, stream, Zb[cur], C);
    hipLaunchKernelGGL(k_cholinv, dim3(1), dim3(512), 0, stream, C, Rinv);
    int o = (cur + 1) % 6;
    hipLaunchKernelGGL(k_gemmSR, dim3(32), dim3(256), 0, stream, Zb[cur], Rinv, Zb[o]);
    cur = o;
  };
  auto rrmid = [&](double* cutp) {
    int y = (cur + 1) % 6;
    gemmGZ(Zb[cur], nullptr, Zb[y], nullptr, 1.f, 0.f, 0.f);   // Y = G S
    hipLaunchKernelGGL(k_xty, dim3(25), dim3(256), 0, stream, Zb[cur], Zb[y], Mm);
    hipLaunchKernelGGL(k_jacobi, dim3(1), dim3(1024), 0, stream,
                       Mm, U, perm, cutp, 2, 0);
  };
  auto rrfinal = [&](double* cutp) {
    int y = (cur + 1) % 6;
    gemmGZ(Zb[cur], nullptr, Zb[y], nullptr, 1.f, 0.f, 0.f);   // Y = G S
    hipLaunchKernelGGL(k_xty, dim3(25), dim3(256), 0, stream, Zb[cur], Zb[y], Mm);
    hipLaunchKernelGGL(k_jacobi, dim3(1), dim3(1024), 0, stream,
                       Mm, U, perm, cutp, 5, 1);
    hipLaunchKernelGGL(k_compose, dim3(16), dim3(256), 0, stream,
                       Zb[cur], U, perm, Vtop);
  };

  const float* hin = x;
  float* hout = hA;
  for (int l = 0; l < 3; l++) {
    hipLaunchKernelGGL(k_linT, dim3(GRID_ROWS), dim3(256), 0, stream,
                       hin, Wl[l], (const float*)nullptr, hl, 64, 0);
    hipMemsetAsync(mus, 0, 16 * 64 * 4, stream);
    hipLaunchKernelGGL(k_meanslot, dim3(16, 8), dim3(256), 0, stream, hl, src, mus);
    hipMemsetAsync(T, 0, (size_t)NB * NB * 4, stream);
    hipLaunchKernelGGL(k_gram, dim3(136, 5), dim3(256), 0, stream, hl, src, mus, T);
    hipLaunchKernelGGL(k_assembleG, dim3(4096), dim3(256), 0, stream, T, G);
    hipLaunchKernelGGL(k_cut0, dim3(1), dim3(256), 0, stream, G, scal);
    cur = 0;
    hipLaunchKernelGGL(k_initS, dim3((NB * BSUB + 255) / 256), dim3(256), 0, stream, Zb[cur]);
    chunk(10, &scal[0]); cholqr();
    rrmid(&scal[1]);
    chunk(13, &scal[1]); cholqr();
    chunk(13, &scal[1]); cholqr();
    rrfinal(&scal[2]);
    hipLaunchKernelGGL(k_projlin, dim3(GRID_ROWS), dim3(256), 0, stream,
                       hl, src, Vtop, Wl[l], bl[l], hout);
    hin = hout;
    hout = (hout == hA) ? hB : hA;
  }
  hipLaunchKernelGGL(k_linT, dim3(GRID_ROWS), dim3(256), 0, stream,
                     hin, Wfc, bfc, hl, NCLS, 0);
  hipLaunchKernelGGL(k_logsoftmax, dim3((NNODES + 255) / 256), dim3(256), 0, stream,
                     hl, outp);
}

// Round 10
// 11629.302 us; speedup vs baseline: 1.5180x; 1.0615x over previous
//
#include <hip/hip_runtime.h>
#include <cmath>

#define NNODES 20000
#define FD 64
#define EPN 15      // regular edges per node
#define NB 1024     // DEG * F
#define BSUB 80     // subspace width (top-64 + 16 buffer)
#define NCLS 16

// ---------------------------------------------------------------------------
// out[n][o] = relu?( sum_j X[n][j] * W[o][j] + bias[o] ), X: [N,64], W: [ncol,64]
__global__ __launch_bounds__(256) void k_linT(const float* __restrict__ X,
    const float* __restrict__ W, const float* __restrict__ bias,
    float* __restrict__ out, int ncol, int relu)
{
  __shared__ float Wsh[64][65];
  __shared__ float Xsh[64][65];
  int t = threadIdx.x;
  int r0 = blockIdx.x * 64;
  for (int idx = t; idx < ncol * 64; idx += 256) Wsh[idx >> 6][idx & 63] = W[idx];
  for (int idx = t; idx < 64 * 64; idx += 256) {
    int r = idx >> 6, c = idx & 63;
    Xsh[r][c] = (r0 + r < NNODES) ? X[(size_t)(r0 + r) * 64 + c] : 0.f;
  }
  __syncthreads();
  for (int idx = t; idx < 64 * ncol; idx += 256) {
    int r = idx / ncol, o = idx % ncol;
    float acc = 0.f;
    #pragma unroll
    for (int j = 0; j < 64; j++) acc += Xsh[r][j] * Wsh[o][j];
    if (bias) acc += bias[o];
    if (relu) acc = fmaxf(acc, 0.f);
    if (r0 + r < NNODES) out[(size_t)(r0 + r) * ncol + o] = acc;
  }
}

// ---------------------------------------------------------------------------
__global__ __launch_bounds__(256) void k_meanslot(const float* __restrict__ hl,
    const int* __restrict__ src, float* __restrict__ mus)
{
  int k = blockIdx.x;          // slot 0..15
  int part = blockIdx.y;       // 8 parts x 2500 nodes
  int t = threadIdx.x;
  int c = t & 63, sub = t >> 6;
  int d0 = part * 2500;
  float acc = 0.f;
  for (int d = d0 + sub; d < d0 + 2500; d += 4) {
    int row = (k < EPN) ? src[d * EPN + k] : d;
    acc += hl[(size_t)row * 64 + c];
  }
  __shared__ float red[4][64];
  red[sub][c] = acc;
  __syncthreads();
  if (t < 64) {
    float s = red[0][t] + red[1][t] + red[2][t] + red[3][t];
    atomicAdd(&mus[k * 64 + t], s * (1.f / 20000.f));
  }
}

// ---------------------------------------------------------------------------
__global__ __launch_bounds__(256) void k_gram(const float* __restrict__ hl,
    const int* __restrict__ src, const float* __restrict__ mus,
    float* __restrict__ T)
{
  __shared__ float Ash[64][64];
  __shared__ float Bsh[64][64];
  __shared__ float muA[64], muB[64];
  int t = threadIdx.x;
  int pr = blockIdx.x, i = 0, rem = pr;
  for (int ii = 0; ii < 16; ii++) {
    int cnt = 16 - ii;
    if (rem < cnt) { i = ii; break; }
    rem -= cnt;
  }
  int j = i + rem;
  if (t < 64) muA[t] = mus[i * 64 + t];
  else if (t < 128) muB[t - 64] = mus[j * 64 + (t - 64)];
  float acc[4][4] = {};
  int a0 = (t & 15) * 4, b0 = (t >> 4) * 4;
  int d0 = blockIdx.y * 4000, d1 = d0 + 4000;
  for (int dc = d0; dc < d1; dc += 64) {
    __syncthreads();
    for (int item = t; item < 1024; item += 256) {
      int rr = item >> 4, f4 = item & 15;
      int d = dc + rr;
      float4 va = make_float4(0.f, 0.f, 0.f, 0.f);
      float4 vb = va;
      if (d < d1) {
        int ra = (i < EPN) ? src[d * EPN + i] : d;
        int rb = (j < EPN) ? src[d * EPN + j] : d;
        va = ((const float4*)hl)[(size_t)ra * 16 + f4];
        vb = ((const float4*)hl)[(size_t)rb * 16 + f4];
        int cb = f4 * 4;
        va.x -= muA[cb]; va.y -= muA[cb + 1]; va.z -= muA[cb + 2]; va.w -= muA[cb + 3];
        vb.x -= muB[cb]; vb.y -= muB[cb + 1]; vb.z -= muB[cb + 2]; vb.w -= muB[cb + 3];
      }
      ((float4*)&Ash[rr][0])[f4] = va;
      ((float4*)&Bsh[rr][0])[f4] = vb;
    }
    __syncthreads();
    for (int dd = 0; dd < 64; dd++) {
      float av[4], bv[4];
      #pragma unroll
      for (int u = 0; u < 4; u++) av[u] = Ash[dd][a0 + u];
      #pragma unroll
      for (int u = 0; u < 4; u++) bv[u] = Bsh[dd][b0 + u];
      #pragma unroll
      for (int x = 0; x < 4; x++)
        #pragma unroll
        for (int y = 0; y < 4; y++) acc[x][y] += av[x] * bv[y];
    }
  }
  #pragma unroll
  for (int x = 0; x < 4; x++)
    #pragma unroll
    for (int y = 0; y < 4; y++)
      atomicAdd(&T[(size_t)(i * 64 + a0 + x) * NB + (j * 64 + b0 + y)], acc[x][y]);
}

// ---------------------------------------------------------------------------
__global__ __launch_bounds__(256) void k_assembleG(const float* __restrict__ T,
    float* __restrict__ G)
{
  size_t idx = (size_t)blockIdx.x * 256 + threadIdx.x;
  int p = (int)(idx >> 10), q = (int)(idx & 1023);
  int ti = p >> 6, tj = q >> 6;
  float v = (ti <= tj) ? T[idx] : T[((size_t)q << 10) | (size_t)p];
  G[idx] = v * (1.f / 256.f);
}

__global__ void k_cut0(const float* __restrict__ G, double* __restrict__ scal)
{
  __shared__ float red[256];
  float m = 0.f;
  for (int p = threadIdx.x; p < NB; p += 256) m = fmaxf(m, G[(size_t)p * NB + p]);
  red[threadIdx.x] = m;
  __syncthreads();
  for (int s = 128; s; s >>= 1) {
    if (threadIdx.x < s) red[threadIdx.x] = fmaxf(red[threadIdx.x], red[threadIdx.x + s]);
    __syncthreads();
  }
  if (threadIdx.x == 0) scal[0] = 0.9 * (double)red[0];
}

__global__ void k_initS(float* __restrict__ S)
{
  int idx = blockIdx.x * 256 + threadIdx.x;
  if (idx < NB * BSUB) {
    unsigned u = (unsigned)(idx + 1) * 2654435761u;
    u ^= u >> 16; u *= 2246822519u; u ^= u >> 13; u *= 3266489917u; u ^= u >> 16;
    S[idx] = ((float)u * (1.f / 4294967296.f)) - 0.5f;
  }
}

// ---------------------------------------------------------------------------
// Fused G@Z with split-K + in-kernel combine (fire-and-forget).
__global__ __launch_bounds__(256) void k_gzfused(const float* __restrict__ G,
    const float* __restrict__ Z, const float* __restrict__ Zp,
    float* __restrict__ P, float* __restrict__ out, int* __restrict__ cnt,
    const double* __restrict__ cptr, float s1, float s2, float s3)
{
  __shared__ float Gs[32][68];
  __shared__ float Zs[64][84];
  __shared__ int lastf;
  int t = threadIdx.x;
  int r0b = blockIdx.x;
  int r0 = r0b * 32;
  int kz = blockIdx.y;
  int cg = t & 15, rg = t >> 4;
  float acc0[5] = {}, acc1[5] = {};
  for (int k0 = kz * 128; k0 < kz * 128 + 128; k0 += 64) {
    __syncthreads();
    #pragma unroll
    for (int s = 0; s < 2; s++) {
      int item = t + s * 256;
      int rr = item >> 4, f4 = item & 15;
      float4 g = ((const float4*)G)[(size_t)(r0 + rr) * 256 + (k0 >> 2) + f4];
      *(float4*)&Gs[rr][f4 * 4] = g;
    }
    #pragma unroll
    for (int s = 0; s < 5; s++) {
      int item = t + s * 256;
      int rr = item / 20, f4 = item % 20;
      float4 z = ((const float4*)Z)[(size_t)(k0 + rr) * 20 + f4];
      *(float4*)&Zs[rr][f4 * 4] = z;
    }
    __syncthreads();
    for (int kk = 0; kk < 64; kk++) {
      float g0 = Gs[rg * 2 + 0][kk];
      float g1 = Gs[rg * 2 + 1][kk];
      float z[5];
      #pragma unroll
      for (int m = 0; m < 5; m++) z[m] = Zs[kk][cg * 5 + m];
      #pragma unroll
      for (int m = 0; m < 5; m++) { acc0[m] += g0 * z[m]; acc1[m] += g1 * z[m]; }
    }
  }
  size_t base = (size_t)kz * (NB * BSUB) + (size_t)(r0 + rg * 2) * BSUB + cg * 5;
  #pragma unroll
  for (int m = 0; m < 5; m++) P[base + m] = acc0[m];
  #pragma unroll
  for (int m = 0; m < 5; m++) P[base + BSUB + m] = acc1[m];
  __threadfence();
  __syncthreads();
  if (t == 0) {
    int old = atomicAdd(&cnt[r0b], 1);
    lastf = (old == 7) ? 1 : 0;
  }
  __syncthreads();
  if (!lastf) return;
  __threadfence();
  float coef = s1;
  if (cptr) coef = s1 * (float)(2.0 / cptr[0]);
  const float4* P4 = (const float4*)P;
  for (int idx = t; idx < 640; idx += 256) {
    size_t o4 = (size_t)r0 * 20 + idx;
    float4 a = P4[o4];
    #pragma unroll
    for (int u = 1; u < 8; u++) {
      float4 b = P4[(size_t)u * 20480 + o4];
      a.x += b.x; a.y += b.y; a.z += b.z; a.w += b.w;
    }
    float4 z = ((const float4*)Z)[o4];
    float4 o;
    o.x = coef * a.x + s2 * z.x;
    o.y = coef * a.y + s2 * z.y;
    o.z = coef * a.z + s2 * z.z;
    o.w = coef * a.w + s2 * z.w;
    if (s3 != 0.f) {
      float4 zp = ((const float4*)Zp)[o4];
      o.x += s3 * zp.x; o.y += s3 * zp.y; o.z += s3 * zp.z; o.w += s3 * zp.w;
    }
    ((float4*)out)[o4] = o;
  }
  __syncthreads();
  if (t == 0) cnt[r0b] = 0;
}

// C (f64) = S^T S
__global__ void k_syrk(const float* __restrict__ S, double* __restrict__ C)
{
  int idx = blockIdx.x * 256 + threadIdx.x;
  if (idx >= BSUB * BSUB) return;
  int a = idx / BSUB, b = idx % BSUB;
  double acc = 0.0;
  for (int i = 0; i < NB; i++)
    acc += (double)S[(size_t)i * BSUB + a] * (double)S[(size_t)i * BSUB + b];
  C[idx] = acc;
}

// M (f32, f64 accum) = X^T Y
__global__ void k_xty(const float* __restrict__ X, const float* __restrict__ Y,
                      float* __restrict__ M)
{
  int idx = blockIdx.x * 256 + threadIdx.x;
  if (idx >= BSUB * BSUB) return;
  int a = idx / BSUB, b = idx % BSUB;
  double acc = 0.0;
  for (int i = 0; i < NB; i++)
    acc += (double)X[(size_t)i * BSUB + a] * (double)Y[(size_t)i * BSUB + b];
  M[idx] = (float)acc;
}

// ---------------------------------------------------------------------------
// fused Cholesky (f64, LDS) + triangular inverse -> Rinv (f32).
// TWO pivot columns eliminated per barrier (see R9).
__global__ __launch_bounds__(512) void k_cholinv(const double* __restrict__ Cin,
    float* __restrict__ Rinv)
{
  __shared__ double R[BSUB][BSUB + 1];   // 51.8 KB
  __shared__ double rownew[2][BSUB];
  __shared__ double dinv[BSUB];
  __shared__ float X[BSUB][BSUB + 1];    // 25.9 KB
  int t = threadIdx.x;
  for (int idx = t; idx < BSUB * BSUB; idx += 512)
    R[idx / BSUB][idx % BSUB] = Cin[idx];
  __syncthreads();
  double flr0 = 1e-30 * (fabs(R[0][0]) + 1e-280);
  int prevrow = -1;
  int pb = 0;
  int k = 0;
  while (k < BSUB - 1) {
    int nrem = BSUB - 1 - k;                  // rows k+1..BSUB-1
    int total = (nrem * (nrem + 1)) >> 1;
    int cplen = (prevrow >= 0) ? (BSUB - prevrow) : 0;
    double piv = R[k][k];
    if (piv < flr0) piv = flr0;
    double rp = 1.0 / piv;
    bool pair = (k + 1 < BSUB - 1);
    if (pair) {
      double dk1 = R[k][k + 1];
      double p1 = R[k + 1][k + 1] - dk1 * dk1 * rp;
      if (p1 < flr0) p1 = flr0;
      double rp1 = 1.0 / p1;
      for (int idx = t; idx < total + cplen; idx += 512) {
        if (idx < total) {
          float nf = 2.f * (float)nrem + 1.f;
          int a = (int)((nf - sqrtf(nf * nf - 8.f * (float)idx)) * 0.5f);
          while (a > 0 && a * nrem - ((a * (a - 1)) >> 1) > idx) a--;
          while ((a + 1) * nrem - (((a + 1) * a) >> 1) <= idx) a++;
          int off = idx - (a * nrem - ((a * (a - 1)) >> 1));
          int i2 = k + 1 + a, j2 = i2 + off;
          if (a == 0) {
            rownew[pb][j2] = R[k + 1][j2] - dk1 * R[k][j2] * rp;
          } else {
            double v = R[i2][j2] - R[k][i2] * R[k][j2] * rp;
            double R1i = R[k + 1][i2] - dk1 * R[k][i2] * rp;
            double R1j = R[k + 1][j2] - dk1 * R[k][j2] * rp;
            v -= R1i * R1j * rp1;
            R[i2][j2] = v;
          }
        } else {
          int j = prevrow + (idx - total);
          R[prevrow][j] = rownew[pb ^ 1][j];
        }
      }
      __syncthreads();
      prevrow = k + 1; pb ^= 1; k += 2;
    } else {
      for (int idx = t; idx < total + cplen; idx += 512) {
        if (idx < total) {
          float nf = 2.f * (float)nrem + 1.f;
          int a = (int)((nf - sqrtf(nf * nf - 8.f * (float)idx)) * 0.5f);
          while (a > 0 && a * nrem - ((a * (a - 1)) >> 1) > idx) a--;
          while ((a + 1) * nrem - (((a + 1) * a) >> 1) <= idx) a++;
          int off = idx - (a * nrem - ((a * (a - 1)) >> 1));
          int i2 = k + 1 + a, j2 = i2 + off;
          R[i2][j2] -= R[k][i2] * R[k][j2] * rp;
        } else {
          int j = prevrow + (idx - total);
          R[prevrow][j] = rownew[pb ^ 1][j];
        }
      }
      __syncthreads();
      prevrow = -1; k += 1;
    }
  }
  if (prevrow >= 0) {
    for (int j = prevrow + t; j < BSUB; j += 512) R[prevrow][j] = rownew[pb ^ 1][j];
    __syncthreads();
  }
  if (t < BSUB) {
    double piv = R[t][t];
    if (piv < flr0) piv = flr0;
    dinv[t] = 1.0 / sqrt(piv);
  }
  __syncthreads();
  for (int idx = t; idx < BSUB * BSUB; idx += 512) {
    int kk = idx / BSUB, j = idx % BSUB;
    if (j > kk) R[kk][j] *= dinv[kk];
  }
  __syncthreads();
  if (t < BSUB) R[t][t] = 1.0 / dinv[t];
  __syncthreads();
  if (t < BSUB) {
    int j = t;
    X[j][j] = (float)dinv[j];
    for (int i = j - 1; i >= 0; i--) {
      double s = 0.0;
      for (int k2 = i + 1; k2 <= j; k2++) s += R[i][k2] * (double)X[k2][j];
      X[i][j] = (float)(-s * dinv[i]);
    }
    for (int i = j + 1; i < BSUB; i++) X[i][j] = 0.f;
  }
  __syncthreads();
  for (int idx = t; idx < BSUB * BSUB; idx += 512)
    Rinv[idx] = X[idx / BSUB][idx % BSUB];
}

// out = S @ Rinv   (1024x80 * 80x80)
__global__ __launch_bounds__(256) void k_gemmSR(const float* __restrict__ S,
    const float* __restrict__ Rinv, float* __restrict__ out)
{
  __shared__ float Rsh[BSUB][84];
  int t = threadIdx.x;
  for (int idx = t; idx < BSUB * BSUB; idx += 256)
    Rsh[idx / BSUB][idx % BSUB] = Rinv[idx];
  __syncthreads();
  int r0 = blockIdx.x * 32;
  int r = t >> 3, c0 = (t & 7) * 10;
  float acc[10] = {};
  const float* srow = &S[(size_t)(r0 + r) * BSUB];
  for (int k = 0; k < BSUB; k++) {
    float s = srow[k];
    #pragma unroll
    for (int m = 0; m < 10; m++) acc[m] += s * Rsh[k][c0 + m];
  }
  #pragma unroll
  for (int m = 0; m < 10; m++) out[(size_t)(r0 + r) * BSUB + c0 + m] = acc[m];
}

// ---------------------------------------------------------------------------
// 80x80 symmetric Jacobi, single block, 1024 threads, TWO barriers per round.
// Paired-column phase B: item = (row-pair, col-pair); loads the 2x2 block
// once, computes the 4 row-rotated intermediates once, writes all 4 outputs.
// Term-for-term identical arithmetic to the (pair, column) formulation.
// Phase A: 40 threads compute params; rest apply Ut rotations of round it-1
// (float2-vectorized, 2 columns/item).
__global__ __launch_bounds__(1024) void k_jacobi(const float* __restrict__ Min,
    float* __restrict__ Uout, int* __restrict__ perm,
    double* __restrict__ cutout, int sweeps, int withU)
{
  __shared__ float Mb[2][BSUB][BSUB + 1];   // 51.8 KB
  __shared__ float Ut[BSUB][BSUB];          // 25.6 KB, Ut[p][k] = U[k][p]
  __shared__ float cs[2][40], sn[2][40];
  __shared__ int pp[2][40], qq[2][40];
  __shared__ float th[BSUB];
  __shared__ int id[BSUB];
  int t = threadIdx.x;
  for (int idx = t; idx < BSUB * BSUB; idx += 1024) {
    int i2 = idx / BSUB, j2 = idx % BSUB;
    Mb[0][i2][j2] = 0.5f * (Min[i2 * BSUB + j2] + Min[j2 * BSUB + i2]);
    if (withU) Ut[i2][j2] = (i2 == j2) ? 1.f : 0.f;
  }
  __syncthreads();
  int nrounds = sweeps * (BSUB - 1);
  int mcur = 0;
  for (int it = 0; it < nrounds; it++) {
    int r = it % (BSUB - 1);
    int pb = it & 1;
    float (*Mc)[BSUB + 1] = Mb[mcur];
    float (*Mn)[BSUB + 1] = Mb[mcur ^ 1];
    // phase A: params (t<40) || Ut rows of round it-1 (float2, 2 cols/item)
    if (t < 40) {
      int p = (t == 0) ? 0 : 1 + (t - 1 + r) % (BSUB - 1);
      int q = 1 + (BSUB - 2 - t + r) % (BSUB - 1);
      if (p > q) { int tmp = p; p = q; q = tmp; }
      pp[pb][t] = p; qq[pb][t] = q;
      float apq = Mc[p][q];
      float c = 1.f, s = 0.f;
      if (fabsf(apq) > 1e-28f) {
        float tau = (Mc[q][q] - Mc[p][p]) / (2.f * apq);
        float tt = copysignf(1.f, tau) / (fabsf(tau) + sqrtf(1.f + tau * tau));
        c = rsqrtf(1.f + tt * tt);
        s = tt * c;
      }
      cs[pb][t] = c; sn[pb][t] = s;
    } else if (withU && it > 0) {
      int ob = pb ^ 1;
      for (int idx = t - 40; idx < 40 * 40; idx += 984) {
        unsigned pr = ((unsigned)idx * 3277u) >> 17;   // idx / 40
        int m = idx - (int)pr * 40;
        int p = pp[ob][pr], q = qq[ob][pr];
        float c = cs[ob][pr], s = sn[ob][pr];
        float2 up = *(float2*)&Ut[p][2 * m];
        float2 uq = *(float2*)&Ut[q][2 * m];
        float2 np, nq;
        np.x = c * up.x - s * uq.x;  np.y = c * up.y - s * uq.y;
        nq.x = s * up.x + c * uq.x;  nq.y = s * up.y + c * uq.y;
        *(float2*)&Ut[p][2 * m] = np;
        *(float2*)&Ut[q][2 * m] = nq;
      }
    }
    __syncthreads();
    // phase B: paired-column out-of-place rotation (1600 items)
    for (int idx = t; idx < 40 * 40; idx += 1024) {
      unsigned pr = ((unsigned)idx * 3277u) >> 17;     // idx / 40
      int j = idx - (int)pr * 40;
      int p = pp[pb][pr], q = qq[pb][pr];
      float c = cs[pb][pr], s = sn[pb][pr];
      int k = pp[pb][j], k2 = qq[pb][j];
      float cj = cs[pb][j], sj = sn[pb][j];
      float mpk = Mc[p][k],  mqk = Mc[q][k];
      float mpk2 = Mc[p][k2], mqk2 = Mc[q][k2];
      float rpk  = c * mpk  - s * mqk;     // row-rotated, col k
      float rqk  = s * mpk  + c * mqk;
      float rpk2 = c * mpk2 - s * mqk2;    // row-rotated, col k2
      float rqk2 = s * mpk2 + c * mqk2;
      Mn[p][k]  = cj * rpk - sj * rpk2;
      Mn[q][k]  = cj * rqk - sj * rqk2;
      Mn[p][k2] = sj * rpk + cj * rpk2;
      Mn[q][k2] = sj * rqk + cj * rqk2;
    }
    __syncthreads();
    mcur ^= 1;
  }
  if (withU) {   // drain: Ut rotations of the last round (float2)
    int ob = (nrounds - 1) & 1;
    for (int idx = t; idx < 40 * 40; idx += 1024) {
      unsigned pr = ((unsigned)idx * 3277u) >> 17;
      int m = idx - (int)pr * 40;
      int p = pp[ob][pr], q = qq[ob][pr];
      float c = cs[ob][pr], s = sn[ob][pr];
      float2 up = *(float2*)&Ut[p][2 * m];
      float2 uq = *(float2*)&Ut[q][2 * m];
      float2 np, nq;
      np.x = c * up.x - s * uq.x;  np.y = c * up.y - s * uq.y;
      nq.x = s * up.x + c * uq.x;  nq.y = s * up.y + c * uq.y;
      *(float2*)&Ut[p][2 * m] = np;
      *(float2*)&Ut[q][2 * m] = nq;
    }
    __syncthreads();
  }
  float (*Mf)[BSUB + 1] = Mb[mcur];
  if (t < BSUB) { th[t] = Mf[t][t]; id[t] = t; }
  __syncthreads();
  if (t == 0) {
    for (int a = 1; a < BSUB; a++) {
      float v = th[a]; int ii = id[a]; int b = a - 1;
      while (b >= 0 && th[b] < v) { th[b + 1] = th[b]; id[b + 1] = id[b]; b--; }
      th[b + 1] = v; id[b + 1] = ii;
    }
    double cut = (double)th[BSUB - 1];
    double lo = 0.02 * (double)th[0];
    if (cut < lo) cut = lo;
    double hi = 0.98 * (double)th[63];
    if (cut > hi) cut = hi;
    cutout[0] = cut;
  }
  __syncthreads();
  if (t < BSUB) perm[t] = id[t];
  if (withU)
    for (int idx = t; idx < BSUB * BSUB; idx += 1024) {
      int k = idx / BSUB, p = idx % BSUB;
      Uout[idx] = Ut[p][k];
    }
}

// out[:, c] = S @ U[:, perm[c]], c < 64
__global__ __launch_bounds__(256) void k_compose(const float* __restrict__ S,
    const float* __restrict__ U, const int* __restrict__ perm,
    float* __restrict__ out)
{
  __shared__ float Ush[BSUB][65];
  int t = threadIdx.x;
  for (int idx = t; idx < BSUB * 64; idx += 256) {
    int jj = idx >> 6, c = idx & 63;
    Ush[jj][c] = U[jj * BSUB + perm[c]];
  }
  __syncthreads();
  int r0 = blockIdx.x * 64;
  for (int oidx = t; oidx < 64 * 64; oidx += 256) {
    int r = oidx >> 6, c = oidx & 63;
    float acc = 0.f;
    const float* srow = &S[(size_t)(r0 + r) * BSUB];
    #pragma unroll 8
    for (int j = 0; j < BSUB; j++) acc += srow[j] * Ush[j][c];
    out[(size_t)(r0 + r) * 64 + c] = acc;
  }
}

// ---------------------------------------------------------------------------
// fused: proj[d] = (1/16) * neigh_d @ Vtop, then hout = relu(proj @ W^T + b)
__global__ __launch_bounds__(256) void k_projlin(const float* __restrict__ hl,
    const int* __restrict__ src, const float* __restrict__ Vtop,
    const float* __restrict__ W, const float* __restrict__ bias,
    float* __restrict__ hout)
{
  __shared__ float Vsh[64][68];
  __shared__ float Hsh[64][68];
  __shared__ float Psh[64][68];
  int t = threadIdx.x;
  int d0 = blockIdx.x * 64;
  int dd = t & 63, pg = t >> 6;
  float acc[16] = {};
  for (int k = 0; k < 16; k++) {
    __syncthreads();
    for (int item = t; item < 1024; item += 256) {
      int rr = item >> 4, f4 = item & 15;
      *(float4*)&Vsh[rr][f4 * 4] = ((const float4*)Vtop)[(size_t)(k * 64 + rr) * 16 + f4];
      int d = d0 + rr;
      float4 v = make_float4(0.f, 0.f, 0.f, 0.f);
      if (d < NNODES) {
        int row = (k < EPN) ? src[d * EPN + k] : d;
        v = ((const float4*)hl)[(size_t)row * 16 + f4];
      }
      *(float4*)&Hsh[rr][f4 * 4] = v;
    }
    __syncthreads();
    for (int j = 0; j < 64; j++) {
      float h = Hsh[dd][j];
      #pragma unroll
      for (int m = 0; m < 16; m++) acc[m] += h * Vsh[j][pg * 16 + m];
    }
  }
  __syncthreads();
  #pragma unroll
  for (int m = 0; m < 16; m++) Psh[dd][pg * 16 + m] = acc[m] * (1.f / 16.f);
  for (int item = t; item < 1024; item += 256) {
    int rr = item >> 4, f4 = item & 15;
    *(float4*)&Vsh[rr][f4 * 4] = ((const float4*)W)[(size_t)rr * 16 + f4];
  }
  __syncthreads();
  if (d0 + dd < NNODES) {
    #pragma unroll
    for (int m = 0; m < 16; m++) {
      int o = pg * 16 + m;
      float a = bias[o];
      for (int j = 0; j < 64; j++) a += Psh[dd][j] * Vsh[o][j];
      hout[(size_t)(d0 + dd) * 64 + o] = fmaxf(a, 0.f);
    }
  }
}

__global__ void k_logsoftmax(const float* __restrict__ logits, float* __restrict__ out)
{
  int n = blockIdx.x * 256 + threadIdx.x;
  if (n >= NNODES) return;
  float v[NCLS];
  float mx = -1e30f;
  #pragma unroll
  for (int c = 0; c < NCLS; c++) { v[c] = logits[(size_t)n * NCLS + c]; mx = fmaxf(mx, v[c]); }
  float se = 0.f;
  #pragma unroll
  for (int c = 0; c < NCLS; c++) se += expf(v[c] - mx);
  float lse = mx + logf(se);
  #pragma unroll
  for (int c = 0; c < NCLS; c++) out[(size_t)n * NCLS + c] = v[c] - lse;
}

// ===========================================================================
extern "C" void kernel_launch(void* const* d_in, const int* in_sizes, int n_in,
                              void* d_out, int out_size, void* d_ws, size_t ws_size,
                              hipStream_t stream)
{
  (void)in_sizes; (void)n_in; (void)out_size; (void)ws_size;
  const float* x = (const float*)d_in[0];
  const int* src = (const int*)d_in[1];
  const float* Wl[3] = { (const float*)d_in[2], (const float*)d_in[4], (const float*)d_in[6] };
  const float* bl[3] = { (const float*)d_in[3], (const float*)d_in[5], (const float*)d_in[7] };
  const float* Wfc = (const float*)d_in[8];
  const float* bfc = (const float*)d_in[9];
  float* outp = (float*)d_out;

  char* w = (char*)d_ws;
  auto alloc = [&](size_t bytes) -> char* {
    char* p = w; w += (bytes + 255) & ~(size_t)255; return p;
  };
  float* hA   = (float*)alloc((size_t)NNODES * 64 * 4);
  float* hB   = (float*)alloc((size_t)NNODES * 64 * 4);
  float* hl   = (float*)alloc((size_t)NNODES * 64 * 4);
  float* T    = (float*)alloc((size_t)NB * NB * 4);
  float* G    = (float*)alloc((size_t)NB * NB * 4);
  float* mus  = (float*)alloc(16 * 64 * 4);
  float* Zb[6];
  for (int i = 0; i < 6; i++) Zb[i] = (float*)alloc((size_t)NB * BSUB * 4);
  float* P     = (float*)alloc((size_t)8 * NB * BSUB * 4);
  int* cnt     = (int*)alloc(32 * 4);
  double* C    = (double*)alloc(BSUB * BSUB * 8);
  float* Rinv  = (float*)alloc(BSUB * BSUB * 4);
  float* Mm    = (float*)alloc(BSUB * BSUB * 4);
  float* U     = (float*)alloc(BSUB * BSUB * 4);
  int* perm    = (int*)alloc(BSUB * 4);
  float* Vtop  = (float*)alloc((size_t)NB * 64 * 4);
  double* scal = (double*)alloc(8 * 8);

  const int GRID_ROWS = (NNODES + 63) / 64;   // 313

  hipMemsetAsync(cnt, 0, 32 * 4, stream);     // combine counters (self-resetting)

  int cur = 0;
  auto gemmGZ = [&](const float* Z, const float* Zp, float* o,
                    const double* cptr, float s1, float s2, float s3) {
    hipLaunchKernelGGL(k_gzfused, dim3(32, 8), dim3(256), 0, stream,
                       G, Z, Zp, P, o, cnt, cptr, s1, s2, s3);
  };
  auto chunk = [&](int deg, const double* cptr) {
    int a = (cur + 1) % 6, b = (cur + 2) % 6;
    float* bufs[3] = { Zb[cur], Zb[a], Zb[b] };
    int ip = 0, ic = 0, io = 1;
    for (int s = 0; s < deg; s++) {
      if (s == 0)
        gemmGZ(bufs[ic], nullptr, bufs[io], cptr, 1.f, -1.f, 0.f);
      else
        gemmGZ(bufs[ic], bufs[ip], bufs[io], cptr, 2.f, -2.f, -1.f);
      if (s == 0) { ip = 0; ic = 1; io = 2; }
      else { int tmp = ip; ip = ic; ic = io; io = tmp; }
    }
    int sel = (deg - 1) % 3;
    cur = (sel == 0) ? a : (sel == 1) ? b : cur;
  };
  auto cholqr = [&]() {
    hipLaunchKernelGGL(k_syrk, dim3(25), dim3(256), 0, stream, Zb[cur], C);
    hipLaunchKernelGGL(k_cholinv, dim3(1), dim3(512), 0, stream, C, Rinv);
    int o = (cur + 1) % 6;
    hipLaunchKernelGGL(k_gemmSR, dim3(32), dim3(256), 0, stream, Zb[cur], Rinv, Zb[o]);
    cur = o;
  };
  auto rrmid = [&](double* cutp) {
    int y = (cur + 1) % 6;
    gemmGZ(Zb[cur], nullptr, Zb[y], nullptr, 1.f, 0.f, 0.f);   // Y = G S
    hipLaunchKernelGGL(k_xty, dim3(25), dim3(256), 0, stream, Zb[cur], Zb[y], Mm);
    hipLaunchKernelGGL(k_jacobi, dim3(1), dim3(1024), 0, stream,
                       Mm, U, perm, cutp, 2, 0);
  };
  auto rrfinal = [&](double* cutp) {
    int y = (cur + 1) % 6;
    gemmGZ(Zb[cur], nullptr, Zb[y], nullptr, 1.f, 0.f, 0.f);   // Y = G S
    hipLaunchKernelGGL(k_xty, dim3(25), dim3(256), 0, stream, Zb[cur], Zb[y], Mm);
    hipLaunchKernelGGL(k_jacobi, dim3(1), dim3(1024), 0, stream,
                       Mm, U, perm, cutp, 5, 1);
    hipLaunchKernelGGL(k_compose, dim3(16), dim3(256), 0, stream,
                       Zb[cur], U, perm, Vtop);
  };

  const float* hin = x;
  float* hout = hA;
  for (int l = 0; l < 3; l++) {
    hipLaunchKernelGGL(k_linT, dim3(GRID_ROWS), dim3(256), 0, stream,
                       hin, Wl[l], (const float*)nullptr, hl, 64, 0);
    hipMemsetAsync(mus, 0, 16 * 64 * 4, stream);
    hipLaunchKernelGGL(k_meanslot, dim3(16, 8), dim3(256), 0, stream, hl, src, mus);
    hipMemsetAsync(T, 0, (size_t)NB * NB * 4, stream);
    hipLaunchKernelGGL(k_gram, dim3(136, 5), dim3(256), 0, stream, hl, src, mus, T);
    hipLaunchKernelGGL(k_assembleG, dim3(4096), dim3(256), 0, stream, T, G);
    hipLaunchKernelGGL(k_cut0, dim3(1), dim3(256), 0, stream, G, scal);
    cur = 0;
    hipLaunchKernelGGL(k_initS, dim3((NB * BSUB + 255) / 256), dim3(256), 0, stream, Zb[cur]);
    chunk(10, &scal[0]); cholqr();
    rrmid(&scal[1]);
    chunk(13, &scal[1]); cholqr();
    chunk(13, &scal[1]); cholqr();
    rrfinal(&scal[2]);
    hipLaunchKernelGGL(k_projlin, dim3(GRID_ROWS), dim3(256), 0, stream,
                       hl, src, Vtop, Wl[l], bl[l], hout);
    hin = hout;
    hout = (hout == hA) ? hB : hA;
  }
  hipLaunchKernelGGL(k_linT, dim3(GRID_ROWS), dim3(256), 0, stream,
                     hin, Wfc, bfc, hl, NCLS, 0);
  hipLaunchKernelGGL(k_logsoftmax, dim3((NNODES + 255) / 256), dim3(256), 0, stream,
                     hl, outp);
}

// Round 13
// 9776.411 us; speedup vs baseline: 1.8058x; 1.1895x over previous
//
#include <hip/hip_runtime.h>
#include <cmath>

#define NNODES 20000
#define FD 64
#define EPN 15      // regular edges per node
#define NB 1024     // DEG * F
#define BSUB 80     // subspace width (top-64 + 16 buffer)
#define NCLS 16

// ---------------------------------------------------------------------------
// out[n][o] = relu?( sum_j X[n][j] * W[o][j] + bias[o] ), X: [N,64], W: [ncol,64]
__global__ __launch_bounds__(256) void k_linT(const float* __restrict__ X,
    const float* __restrict__ W, const float* __restrict__ bias,
    float* __restrict__ out, int ncol, int relu)
{
  __shared__ float Wsh[64][65];
  __shared__ float Xsh[64][65];
  int t = threadIdx.x;
  int r0 = blockIdx.x * 64;
  for (int idx = t; idx < ncol * 64; idx += 256) Wsh[idx >> 6][idx & 63] = W[idx];
  for (int idx = t; idx < 64 * 64; idx += 256) {
    int r = idx >> 6, c = idx & 63;
    Xsh[r][c] = (r0 + r < NNODES) ? X[(size_t)(r0 + r) * 64 + c] : 0.f;
  }
  __syncthreads();
  for (int idx = t; idx < 64 * ncol; idx += 256) {
    int r = idx / ncol, o = idx % ncol;
    float acc = 0.f;
    #pragma unroll
    for (int j = 0; j < 64; j++) acc += Xsh[r][j] * Wsh[o][j];
    if (bias) acc += bias[o];
    if (relu) acc = fmaxf(acc, 0.f);
    if (r0 + r < NNODES) out[(size_t)(r0 + r) * ncol + o] = acc;
  }
}

// ---------------------------------------------------------------------------
__global__ __launch_bounds__(256) void k_meanslot(const float* __restrict__ hl,
    const int* __restrict__ src, float* __restrict__ mus)
{
  int k = blockIdx.x;          // slot 0..15
  int part = blockIdx.y;       // 8 parts x 2500 nodes
  int t = threadIdx.x;
  int c = t & 63, sub = t >> 6;
  int d0 = part * 2500;
  float acc = 0.f;
  for (int d = d0 + sub; d < d0 + 2500; d += 4) {
    int row = (k < EPN) ? src[d * EPN + k] : d;
    acc += hl[(size_t)row * 64 + c];
  }
  __shared__ float red[4][64];
  red[sub][c] = acc;
  __syncthreads();
  if (t < 64) {
    float s = red[0][t] + red[1][t] + red[2][t] + red[3][t];
    atomicAdd(&mus[k * 64 + t], s * (1.f / 20000.f));
  }
}

// ---------------------------------------------------------------------------
__global__ __launch_bounds__(256) void k_gram(const float* __restrict__ hl,
    const int* __restrict__ src, const float* __restrict__ mus,
    float* __restrict__ T)
{
  __shared__ float Ash[64][64];
  __shared__ float Bsh[64][64];
  __shared__ float muA[64], muB[64];
  int t = threadIdx.x;
  int pr = blockIdx.x, i = 0, rem = pr;
  for (int ii = 0; ii < 16; ii++) {
    int cnt = 16 - ii;
    if (rem < cnt) { i = ii; break; }
    rem -= cnt;
  }
  int j = i + rem;
  if (t < 64) muA[t] = mus[i * 64 + t];
  else if (t < 128) muB[t - 64] = mus[j * 64 + (t - 64)];
  float acc[4][4] = {};
  int a0 = (t & 15) * 4, b0 = (t >> 4) * 4;
  int d0 = blockIdx.y * 4000, d1 = d0 + 4000;
  for (int dc = d0; dc < d1; dc += 64) {
    __syncthreads();
    for (int item = t; item < 1024; item += 256) {
      int rr = item >> 4, f4 = item & 15;
      int d = dc + rr;
      float4 va = make_float4(0.f, 0.f, 0.f, 0.f);
      float4 vb = va;
      if (d < d1) {
        int ra = (i < EPN) ? src[d * EPN + i] : d;
        int rb = (j < EPN) ? src[d * EPN + j] : d;
        va = ((const float4*)hl)[(size_t)ra * 16 + f4];
        vb = ((const float4*)hl)[(size_t)rb * 16 + f4];
        int cb = f4 * 4;
        va.x -= muA[cb]; va.y -= muA[cb + 1]; va.z -= muA[cb + 2]; va.w -= muA[cb + 3];
        vb.x -= muB[cb]; vb.y -= muB[cb + 1]; vb.z -= muB[cb + 2]; vb.w -= muB[cb + 3];
      }
      ((float4*)&Ash[rr][0])[f4] = va;
      ((float4*)&Bsh[rr][0])[f4] = vb;
    }
    __syncthreads();
    for (int dd = 0; dd < 64; dd++) {
      float av[4], bv[4];
      #pragma unroll
      for (int u = 0; u < 4; u++) av[u] = Ash[dd][a0 + u];
      #pragma unroll
      for (int u = 0; u < 4; u++) bv[u] = Bsh[dd][b0 + u];
      #pragma unroll
      for (int x = 0; x < 4; x++)
        #pragma unroll
        for (int y = 0; y < 4; y++) acc[x][y] += av[x] * bv[y];
    }
  }
  #pragma unroll
  for (int x = 0; x < 4; x++)
    #pragma unroll
    for (int y = 0; y < 4; y++)
      atomicAdd(&T[(size_t)(i * 64 + a0 + x) * NB + (j * 64 + b0 + y)], acc[x][y]);
}

// ---------------------------------------------------------------------------
__global__ __launch_bounds__(256) void k_assembleG(const float* __restrict__ T,
    float* __restrict__ G)
{
  size_t idx = (size_t)blockIdx.x * 256 + threadIdx.x;
  int p = (int)(idx >> 10), q = (int)(idx & 1023);
  int ti = p >> 6, tj = q >> 6;
  float v = (ti <= tj) ? T[idx] : T[((size_t)q << 10) | (size_t)p];
  G[idx] = v * (1.f / 256.f);
}

// ---------------------------------------------------------------------------
// G2 = G @ G. G is symmetric, so G2[a][b] = sum_d G[d][a]*G[d][b] — Gramian
// pattern: stage contiguous row-chunks of both column panels.
// grid (16,16), 256 threads, 4x4 acc/thread.
__global__ __launch_bounds__(256) void k_gemmG2(const float* __restrict__ G,
    float* __restrict__ G2)
{
  __shared__ float Ash[64][68];
  __shared__ float Bsh[64][68];
  int t = threadIdx.x;
  int bi = blockIdx.x * 64, bj = blockIdx.y * 64;
  int a0 = (t & 15) * 4, b0 = (t >> 4) * 4;
  float acc[4][4] = {};
  for (int d0 = 0; d0 < NB; d0 += 64) {
    __syncthreads();
    for (int item = t; item < 1024; item += 256) {
      int rr = item >> 4, f4 = item & 15;
      *(float4*)&Ash[rr][f4 * 4] =
          ((const float4*)G)[(size_t)(d0 + rr) * 256 + (bi >> 2) + f4];
      *(float4*)&Bsh[rr][f4 * 4] =
          ((const float4*)G)[(size_t)(d0 + rr) * 256 + (bj >> 2) + f4];
    }
    __syncthreads();
    for (int dd = 0; dd < 64; dd++) {
      float av[4], bv[4];
      #pragma unroll
      for (int u = 0; u < 4; u++) av[u] = Ash[dd][a0 + u];
      #pragma unroll
      for (int u = 0; u < 4; u++) bv[u] = Bsh[dd][b0 + u];
      #pragma unroll
      for (int x = 0; x < 4; x++)
        #pragma unroll
        for (int y = 0; y < 4; y++) acc[x][y] += av[x] * bv[y];
    }
  }
  #pragma unroll
  for (int x = 0; x < 4; x++) {
    float4 v = make_float4(acc[x][0], acc[x][1], acc[x][2], acc[x][3]);
    ((float4*)G2)[(size_t)(bi + a0 + x) * 256 + ((bj + b0) >> 2)] = v;
  }
}

// scal[0] = 0.9 * max diag(G) (lambda-scale cutoff), scal[1] = its square
__global__ void k_cut0(const float* __restrict__ G, double* __restrict__ scal)
{
  __shared__ float red[256];
  float m = 0.f;
  for (int p = threadIdx.x; p < NB; p += 256) m = fmaxf(m, G[(size_t)p * NB + p]);
  red[threadIdx.x] = m;
  __syncthreads();
  for (int s = 128; s; s >>= 1) {
    if (threadIdx.x < s) red[threadIdx.x] = fmaxf(red[threadIdx.x], red[threadIdx.x + s]);
    __syncthreads();
  }
  if (threadIdx.x == 0) {
    double c = 0.9 * (double)red[0];
    scal[0] = c;
    scal[1] = c * c;
  }
}

__global__ void k_initS(float* __restrict__ S)
{
  int idx = blockIdx.x * 256 + threadIdx.x;
  if (idx < NB * BSUB) {
    unsigned u = (unsigned)(idx + 1) * 2654435761u;
    u ^= u >> 16; u *= 2246822519u; u ^= u >> 13; u *= 3266489917u; u ^= u >> 16;
    S[idx] = ((float)u * (1.f / 4294967296.f)) - 0.5f;
  }
}

// ---------------------------------------------------------------------------
// Fused A@Z with split-K + in-kernel combine (fire-and-forget). A is G or G2.
__global__ __launch_bounds__(256) void k_gzfused(const float* __restrict__ G,
    const float* __restrict__ Z, const float* __restrict__ Zp,
    float* __restrict__ P, float* __restrict__ out, int* __restrict__ cnt,
    const double* __restrict__ cptr, float s1, float s2, float s3)
{
  __shared__ float Gs[32][68];
  __shared__ float Zs[64][84];
  __shared__ int lastf;
  int t = threadIdx.x;
  int r0b = blockIdx.x;
  int r0 = r0b * 32;
  int kz = blockIdx.y;
  int cg = t & 15, rg = t >> 4;
  float acc0[5] = {}, acc1[5] = {};
  for (int k0 = kz * 128; k0 < kz * 128 + 128; k0 += 64) {
    __syncthreads();
    #pragma unroll
    for (int s = 0; s < 2; s++) {
      int item = t + s * 256;
      int rr = item >> 4, f4 = item & 15;
      float4 g = ((const float4*)G)[(size_t)(r0 + rr) * 256 + (k0 >> 2) + f4];
      *(float4*)&Gs[rr][f4 * 4] = g;
    }
    #pragma unroll
    for (int s = 0; s < 5; s++) {
      int item = t + s * 256;
      int rr = item / 20, f4 = item % 20;
      float4 z = ((const float4*)Z)[(size_t)(k0 + rr) * 20 + f4];
      *(float4*)&Zs[rr][f4 * 4] = z;
    }
    __syncthreads();
    for (int kk = 0; kk < 64; kk++) {
      float g0 = Gs[rg * 2 + 0][kk];
      float g1 = Gs[rg * 2 + 1][kk];
      float z[5];
      #pragma unroll
      for (int m = 0; m < 5; m++) z[m] = Zs[kk][cg * 5 + m];
      #pragma unroll
      for (int m = 0; m < 5; m++) { acc0[m] += g0 * z[m]; acc1[m] += g1 * z[m]; }
    }
  }
  size_t base = (size_t)kz * (NB * BSUB) + (size_t)(r0 + rg * 2) * BSUB + cg * 5;
  #pragma unroll
  for (int m = 0; m < 5; m++) P[base + m] = acc0[m];
  #pragma unroll
  for (int m = 0; m < 5; m++) P[base + BSUB + m] = acc1[m];
  __threadfence();
  __syncthreads();
  if (t == 0) {
    int old = atomicAdd(&cnt[r0b], 1);
    lastf = (old == 7) ? 1 : 0;
  }
  __syncthreads();
  if (!lastf) return;
  __threadfence();
  float coef = s1;
  if (cptr) coef = s1 * (float)(2.0 / cptr[0]);
  const float4* P4 = (const float4*)P;
  for (int idx = t; idx < 640; idx += 256) {
    size_t o4 = (size_t)r0 * 20 + idx;
    float4 a = P4[o4];
    #pragma unroll
    for (int u = 1; u < 8; u++) {
      float4 b = P4[(size_t)u * 20480 + o4];
      a.x += b.x; a.y += b.y; a.z += b.z; a.w += b.w;
    }
    float4 z = ((const float4*)Z)[o4];
    float4 o;
    o.x = coef * a.x + s2 * z.x;
    o.y = coef * a.y + s2 * z.y;
    o.z = coef * a.z + s2 * z.z;
    o.w = coef * a.w + s2 * z.w;
    if (s3 != 0.f) {
      float4 zp = ((const float4*)Zp)[o4];
      o.x += s3 * zp.x; o.y += s3 * zp.y; o.z += s3 * zp.z; o.w += s3 * zp.w;
    }
    ((float4*)out)[o4] = o;
  }
  __syncthreads();
  if (t == 0) cnt[r0b] = 0;
}

// C (f64) = S^T S
__global__ void k_syrk(const float* __restrict__ S, double* __restrict__ C)
{
  int idx = blockIdx.x * 256 + threadIdx.x;
  if (idx >= BSUB * BSUB) return;
  int a = idx / BSUB, b = idx % BSUB;
  double acc = 0.0;
  for (int i = 0; i < NB; i++)
    acc += (double)S[(size_t)i * BSUB + a] * (double)S[(size_t)i * BSUB + b];
  C[idx] = acc;
}

// M (f32, f64 accum) = X^T Y
__global__ void k_xty(const float* __restrict__ X, const float* __restrict__ Y,
                      float* __restrict__ M)
{
  int idx = blockIdx.x * 256 + threadIdx.x;
  if (idx >= BSUB * BSUB) return;
  int a = idx / BSUB, b = idx % BSUB;
  double acc = 0.0;
  for (int i = 0; i < NB; i++)
    acc += (double)X[(size_t)i * BSUB + a] * (double)Y[(size_t)i * BSUB + b];
  M[idx] = (float)acc;
}

// ---------------------------------------------------------------------------
// fused Cholesky (f64, LDS) + triangular inverse -> Rinv (f32).
// TWO pivot columns eliminated per barrier (see R9).
__global__ __launch_bounds__(512) void k_cholinv(const double* __restrict__ Cin,
    float* __restrict__ Rinv)
{
  __shared__ double R[BSUB][BSUB + 1];   // 51.8 KB
  __shared__ double rownew[2][BSUB];
  __shared__ double dinv[BSUB];
  __shared__ float X[BSUB][BSUB + 1];    // 25.9 KB
  int t = threadIdx.x;
  for (int idx = t; idx < BSUB * BSUB; idx += 512)
    R[idx / BSUB][idx % BSUB] = Cin[idx];
  __syncthreads();
  double flr0 = 1e-30 * (fabs(R[0][0]) + 1e-280);
  int prevrow = -1;
  int pb = 0;
  int k = 0;
  while (k < BSUB - 1) {
    int nrem = BSUB - 1 - k;                  // rows k+1..BSUB-1
    int total = (nrem * (nrem + 1)) >> 1;
    int cplen = (prevrow >= 0) ? (BSUB - prevrow) : 0;
    double piv = R[k][k];
    if (piv < flr0) piv = flr0;
    double rp = 1.0 / piv;
    bool pair = (k + 1 < BSUB - 1);
    if (pair) {
      double dk1 = R[k][k + 1];
      double p1 = R[k + 1][k + 1] - dk1 * dk1 * rp;
      if (p1 < flr0) p1 = flr0;
      double rp1 = 1.0 / p1;
      for (int idx = t; idx < total + cplen; idx += 512) {
        if (idx < total) {
          float nf = 2.f * (float)nrem + 1.f;
          int a = (int)((nf - sqrtf(nf * nf - 8.f * (float)idx)) * 0.5f);
          while (a > 0 && a * nrem - ((a * (a - 1)) >> 1) > idx) a--;
          while ((a + 1) * nrem - (((a + 1) * a) >> 1) <= idx) a++;
          int off = idx - (a * nrem - ((a * (a - 1)) >> 1));
          int i2 = k + 1 + a, j2 = i2 + off;
          if (a == 0) {
            rownew[pb][j2] = R[k + 1][j2] - dk1 * R[k][j2] * rp;
          } else {
            double v = R[i2][j2] - R[k][i2] * R[k][j2] * rp;
            double R1i = R[k + 1][i2] - dk1 * R[k][i2] * rp;
            double R1j = R[k + 1][j2] - dk1 * R[k][j2] * rp;
            v -= R1i * R1j * rp1;
            R[i2][j2] = v;
          }
        } else {
          int j = prevrow + (idx - total);
          R[prevrow][j] = rownew[pb ^ 1][j];
        }
      }
      __syncthreads();
      prevrow = k + 1; pb ^= 1; k += 2;
    } else {
      for (int idx = t; idx < total + cplen; idx += 512) {
        if (idx < total) {
          float nf = 2.f * (float)nrem + 1.f;
          int a = (int)((nf - sqrtf(nf * nf - 8.f * (float)idx)) * 0.5f);
          while (a > 0 && a * nrem - ((a * (a - 1)) >> 1) > idx) a--;
          while ((a + 1) * nrem - (((a + 1) * a) >> 1) <= idx) a++;
          int off = idx - (a * nrem - ((a * (a - 1)) >> 1));
          int i2 = k + 1 + a, j2 = i2 + off;
          R[i2][j2] -= R[k][i2] * R[k][j2] * rp;
        } else {
          int j = prevrow + (idx - total);
          R[prevrow][j] = rownew[pb ^ 1][j];
        }
      }
      __syncthreads();
      prevrow = -1; k += 1;
    }
  }
  if (prevrow >= 0) {
    for (int j = prevrow + t; j < BSUB; j += 512) R[prevrow][j] = rownew[pb ^ 1][j];
    __syncthreads();
  }
  if (t < BSUB) {
    double piv = R[t][t];
    if (piv < flr0) piv = flr0;
    dinv[t] = 1.0 / sqrt(piv);
  }
  __syncthreads();
  for (int idx = t; idx < BSUB * BSUB; idx += 512) {
    int kk = idx / BSUB, j = idx % BSUB;
    if (j > kk) R[kk][j] *= dinv[kk];
  }
  __syncthreads();
  if (t < BSUB) R[t][t] = 1.0 / dinv[t];
  __syncthreads();
  if (t < BSUB) {
    int j = t;
    X[j][j] = (float)dinv[j];
    for (int i = j - 1; i >= 0; i--) {
      double s = 0.0;
      for (int k2 = i + 1; k2 <= j; k2++) s += R[i][k2] * (double)X[k2][j];
      X[i][j] = (float)(-s * dinv[i]);
    }
    for (int i = j + 1; i < BSUB; i++) X[i][j] = 0.f;
  }
  __syncthreads();
  for (int idx = t; idx < BSUB * BSUB; idx += 512)
    Rinv[idx] = X[idx / BSUB][idx % BSUB];
}

// out = S @ Rinv   (1024x80 * 80x80)
__global__ __launch_bounds__(256) void k_gemmSR(const float* __restrict__ S,
    const float* __restrict__ Rinv, float* __restrict__ out)
{
  __shared__ float Rsh[BSUB][84];
  int t = threadIdx.x;
  for (int idx = t; idx < BSUB * BSUB; idx += 256)
    Rsh[idx / BSUB][idx % BSUB] = Rinv[idx];
  __syncthreads();
  int r0 = blockIdx.x * 32;
  int r = t >> 3, c0 = (t & 7) * 10;
  float acc[10] = {};
  const float* srow = &S[(size_t)(r0 + r) * BSUB];
  for (int k = 0; k < BSUB; k++) {
    float s = srow[k];
    #pragma unroll
    for (int m = 0; m < 10; m++) acc[m] += s * Rsh[k][c0 + m];
  }
  #pragma unroll
  for (int m = 0; m < 10; m++) out[(size_t)(r0 + r) * BSUB + c0 + m] = acc[m];
}

// ---------------------------------------------------------------------------
// 80x80 symmetric Jacobi, single block, 1024 threads (see R10).
// cutout[0] = lambda-scale cutoff, cutout[1] = its square.
__global__ __launch_bounds__(1024) void k_jacobi(const float* __restrict__ Min,
    float* __restrict__ Uout, int* __restrict__ perm,
    double* __restrict__ cutout, int sweeps, int withU)
{
  __shared__ float Mb[2][BSUB][BSUB + 1];   // 51.8 KB
  __shared__ float Ut[BSUB][BSUB];          // 25.6 KB, Ut[p][k] = U[k][p]
  __shared__ float cs[2][40], sn[2][40];
  __shared__ int pp[2][40], qq[2][40];
  __shared__ float th[BSUB];
  __shared__ int id[BSUB];
  int t = threadIdx.x;
  for (int idx = t; idx < BSUB * BSUB; idx += 1024) {
    int i2 = idx / BSUB, j2 = idx % BSUB;
    Mb[0][i2][j2] = 0.5f * (Min[i2 * BSUB + j2] + Min[j2 * BSUB + i2]);
    if (withU) Ut[i2][j2] = (i2 == j2) ? 1.f : 0.f;
  }
  __syncthreads();
  int nrounds = sweeps * (BSUB - 1);
  int mcur = 0;
  for (int it = 0; it < nrounds; it++) {
    int r = it % (BSUB - 1);
    int pb = it & 1;
    float (*Mc)[BSUB + 1] = Mb[mcur];
    float (*Mn)[BSUB + 1] = Mb[mcur ^ 1];
    if (t < 40) {
      int p = (t == 0) ? 0 : 1 + (t - 1 + r) % (BSUB - 1);
      int q = 1 + (BSUB - 2 - t + r) % (BSUB - 1);
      if (p > q) { int tmp = p; p = q; q = tmp; }
      pp[pb][t] = p; qq[pb][t] = q;
      float apq = Mc[p][q];
      float c = 1.f, s = 0.f;
      if (fabsf(apq) > 1e-28f) {
        float tau = (Mc[q][q] - Mc[p][p]) / (2.f * apq);
        float tt = copysignf(1.f, tau) / (fabsf(tau) + sqrtf(1.f + tau * tau));
        c = rsqrtf(1.f + tt * tt);
        s = tt * c;
      }
      cs[pb][t] = c; sn[pb][t] = s;
    } else if (withU && it > 0) {
      int ob = pb ^ 1;
      for (int idx = t - 40; idx < 40 * 40; idx += 984) {
        unsigned pr = ((unsigned)idx * 3277u) >> 17;   // idx / 40
        int m = idx - (int)pr * 40;
        int p = pp[ob][pr], q = qq[ob][pr];
        float c = cs[ob][pr], s = sn[ob][pr];
        float2 up = *(float2*)&Ut[p][2 * m];
        float2 uq = *(float2*)&Ut[q][2 * m];
        float2 np, nq;
        np.x = c * up.x - s * uq.x;  np.y = c * up.y - s * uq.y;
        nq.x = s * up.x + c * uq.x;  nq.y = s * up.y + c * uq.y;
        *(float2*)&Ut[p][2 * m] = np;
        *(float2*)&Ut[q][2 * m] = nq;
      }
    }
    __syncthreads();
    for (int idx = t; idx < 40 * 40; idx += 1024) {
      unsigned pr = ((unsigned)idx * 3277u) >> 17;     // idx / 40
      int j = idx - (int)pr * 40;
      int p = pp[pb][pr], q = qq[pb][pr];
      float c = cs[pb][pr], s = sn[pb][pr];
      int k = pp[pb][j], k2 = qq[pb][j];
      float cj = cs[pb][j], sj = sn[pb][j];
      float mpk = Mc[p][k],  mqk = Mc[q][k];
      float mpk2 = Mc[p][k2], mqk2 = Mc[q][k2];
      float rpk  = c * mpk  - s * mqk;
      float rqk  = s * mpk  + c * mqk;
      float rpk2 = c * mpk2 - s * mqk2;
      float rqk2 = s * mpk2 + c * mqk2;
      Mn[p][k]  = cj * rpk - sj * rpk2;
      Mn[q][k]  = cj * rqk - sj * rqk2;
      Mn[p][k2] = sj * rpk + cj * rpk2;
      Mn[q][k2] = sj * rqk + cj * rqk2;
    }
    __syncthreads();
    mcur ^= 1;
  }
  if (withU) {
    int ob = (nrounds - 1) & 1;
    for (int idx = t; idx < 40 * 40; idx += 1024) {
      unsigned pr = ((unsigned)idx * 3277u) >> 17;
      int m = idx - (int)pr * 40;
      int p = pp[ob][pr], q = qq[ob][pr];
      float c = cs[ob][pr], s = sn[ob][pr];
      float2 up = *(float2*)&Ut[p][2 * m];
      float2 uq = *(float2*)&Ut[q][2 * m];
      float2 np, nq;
      np.x = c * up.x - s * uq.x;  np.y = c * up.y - s * uq.y;
      nq.x = s * up.x + c * uq.x;  nq.y = s * up.y + c * uq.y;
      *(float2*)&Ut[p][2 * m] = np;
      *(float2*)&Ut[q][2 * m] = nq;
    }
    __syncthreads();
  }
  float (*Mf)[BSUB + 1] = Mb[mcur];
  if (t < BSUB) { th[t] = Mf[t][t]; id[t] = t; }
  __syncthreads();
  if (t == 0) {
    for (int a = 1; a < BSUB; a++) {
      float v = th[a]; int ii = id[a]; int b = a - 1;
      while (b >= 0 && th[b] < v) { th[b + 1] = th[b]; id[b + 1] = id[b]; b--; }
      th[b + 1] = v; id[b + 1] = ii;
    }
    double cut = (double)th[BSUB - 1];
    double lo = 0.02 * (double)th[0];
    if (cut < lo) cut = lo;
    double hi = 0.98 * (double)th[63];
    if (cut > hi) cut = hi;
    cutout[0] = cut;
    cutout[1] = cut * cut;
  }
  __syncthreads();
  if (t < BSUB) perm[t] = id[t];
  if (withU)
    for (int idx = t; idx < BSUB * BSUB; idx += 1024) {
      int k = idx / BSUB, p = idx % BSUB;
      Uout[idx] = Ut[p][k];
    }
}

// out[:, c] = S @ U[:, perm[c]], c < 64
__global__ __launch_bounds__(256) void k_compose(const float* __restrict__ S,
    const float* __restrict__ U, const int* __restrict__ perm,
    float* __restrict__ out)
{
  __shared__ float Ush[BSUB][65];
  int t = threadIdx.x;
  for (int idx = t; idx < BSUB * 64; idx += 256) {
    int jj = idx >> 6, c = idx & 63;
    Ush[jj][c] = U[jj * BSUB + perm[c]];
  }
  __syncthreads();
  int r0 = blockIdx.x * 64;
  for (int oidx = t; oidx < 64 * 64; oidx += 256) {
    int r = oidx >> 6, c = oidx & 63;
    float acc = 0.f;
    const float* srow = &S[(size_t)(r0 + r) * BSUB];
    #pragma unroll 8
    for (int j = 0; j < BSUB; j++) acc += srow[j] * Ush[j][c];
    out[(size_t)(r0 + r) * 64 + c] = acc;
  }
}

// ---------------------------------------------------------------------------
// fused: proj[d] = (1/16) * neigh_d @ Vtop, then hout = relu(proj @ W^T + b)
__global__ __launch_bounds__(256) void k_projlin(const float* __restrict__ hl,
    const int* __restrict__ src, const float* __restrict__ Vtop,
    const float* __restrict__ W, const float* __restrict__ bias,
    float* __restrict__ hout)
{
  __shared__ float Vsh[64][68];
  __shared__ float Hsh[64][68];
  __shared__ float Psh[64][68];
  int t = threadIdx.x;
  int d0 = blockIdx.x * 64;
  int dd = t & 63, pg = t >> 6;
  float acc[16] = {};
  for (int k = 0; k < 16; k++) {
    __syncthreads();
    for (int item = t; item < 1024; item += 256) {
      int rr = item >> 4, f4 = item & 15;
      *(float4*)&Vsh[rr][f4 * 4] = ((const float4*)Vtop)[(size_t)(k * 64 + rr) * 16 + f4];
      int d = d0 + rr;
      float4 v = make_float4(0.f, 0.f, 0.f, 0.f);
      if (d < NNODES) {
        int row = (k < EPN) ? src[d * EPN + k] : d;
        v = ((const float4*)hl)[(size_t)row * 16 + f4];
      }
      *(float4*)&Hsh[rr][f4 * 4] = v;
    }
    __syncthreads();
    for (int j = 0; j < 64; j++) {
      float h = Hsh[dd][j];
      #pragma unroll
      for (int m = 0; m < 16; m++) acc[m] += h * Vsh[j][pg * 16 + m];
    }
  }
  __syncthreads();
  #pragma unroll
  for (int m = 0; m < 16; m++) Psh[dd][pg * 16 + m] = acc[m] * (1.f / 16.f);
  for (int item = t; item < 1024; item += 256) {
    int rr = item >> 4, f4 = item & 15;
    *(float4*)&Vsh[rr][f4 * 4] = ((const float4*)W)[(size_t)rr * 16 + f4];
  }
  __syncthreads();
  if (d0 + dd < NNODES) {
    #pragma unroll
    for (int m = 0; m < 16; m++) {
      int o = pg * 16 + m;
      float a = bias[o];
      for (int j = 0; j < 64; j++) a += Psh[dd][j] * Vsh[o][j];
      hout[(size_t)(d0 + dd) * 64 + o] = fmaxf(a, 0.f);
    }
  }
}

__global__ void k_logsoftmax(const float* __restrict__ logits, float* __restrict__ out)
{
  int n = blockIdx.x * 256 + threadIdx.x;
  if (n >= NNODES) return;
  float v[NCLS];
  float mx = -1e30f;
  #pragma unroll
  for (int c = 0; c < NCLS; c++) { v[c] = logits[(size_t)n * NCLS + c]; mx = fmaxf(mx, v[c]); }
  float se = 0.f;
  #pragma unroll
  for (int c = 0; c < NCLS; c++) se += expf(v[c] - mx);
  float lse = mx + logf(se);
  #pragma unroll
  for (int c = 0; c < NCLS; c++) out[(size_t)n * NCLS + c] = v[c] - lse;
}

// ===========================================================================
extern "C" void kernel_launch(void* const* d_in, const int* in_sizes, int n_in,
                              void* d_out, int out_size, void* d_ws, size_t ws_size,
                              hipStream_t stream)
{
  (void)in_sizes; (void)n_in; (void)out_size; (void)ws_size;
  const float* x = (const float*)d_in[0];
  const int* src = (const int*)d_in[1];
  const float* Wl[3] = { (const float*)d_in[2], (const float*)d_in[4], (const float*)d_in[6] };
  const float* bl[3] = { (const float*)d_in[3], (const float*)d_in[5], (const float*)d_in[7] };
  const float* Wfc = (const float*)d_in[8];
  const float* bfc = (const float*)d_in[9];
  float* outp = (float*)d_out;

  char* w = (char*)d_ws;
  auto alloc = [&](size_t bytes) -> char* {
    char* p = w; w += (bytes + 255) & ~(size_t)255; return p;
  };
  float* hA   = (float*)alloc((size_t)NNODES * 64 * 4);
  float* hB   = (float*)alloc((size_t)NNODES * 64 * 4);
  float* hl   = (float*)alloc((size_t)NNODES * 64 * 4);
  float* T    = (float*)alloc((size_t)NB * NB * 4);
  float* G    = (float*)alloc((size_t)NB * NB * 4);
  float* G2   = (float*)alloc((size_t)NB * NB * 4);
  float* mus  = (float*)alloc(16 * 64 * 4);
  float* Zb[6];
  for (int i = 0; i < 6; i++) Zb[i] = (float*)alloc((size_t)NB * BSUB * 4);
  float* P     = (float*)alloc((size_t)8 * NB * BSUB * 4);
  int* cnt     = (int*)alloc(32 * 4);
  double* C    = (double*)alloc(BSUB * BSUB * 8);
  float* Rinv  = (float*)alloc(BSUB * BSUB * 4);
  float* Mm    = (float*)alloc(BSUB * BSUB * 4);
  float* U     = (float*)alloc(BSUB * BSUB * 4);
  int* perm    = (int*)alloc(BSUB * 4);
  float* Vtop  = (float*)alloc((size_t)NB * 64 * 4);
  double* scal = (double*)alloc(16 * 8);

  const int GRID_ROWS = (NNODES + 63) / 64;   // 313

  hipMemsetAsync(cnt, 0, 32 * 4, stream);     // combine counters (self-resetting)

  int cur = 0;
  auto gemmGZ = [&](const float* A, const float* Z, const float* Zp, float* o,
                    const double* cptr, float s1, float s2, float s3) {
    hipLaunchKernelGGL(k_gzfused, dim3(32, 8), dim3(256), 0, stream,
                       A, Z, Zp, P, o, cnt, cptr, s1, s2, s3);
  };
  // Chebyshev chunk of degree `deg` in G2 (= degree 2*deg filter in G).
  // cptr points at the SQUARED cutoff.
  auto chunk2 = [&](int deg, const double* cptr) {
    int a = (cur + 1) % 6, b = (cur + 2) % 6;
    float* bufs[3] = { Zb[cur], Zb[a], Zb[b] };
    int ip = 0, ic = 0, io = 1;
    for (int s = 0; s < deg; s++) {
      if (s == 0)
        gemmGZ(G2, bufs[ic], nullptr, bufs[io], cptr, 1.f, -1.f, 0.f);
      else
        gemmGZ(G2, bufs[ic], bufs[ip], bufs[io], cptr, 2.f, -2.f, -1.f);
      if (s == 0) { ip = 0; ic = 1; io = 2; }
      else { int tmp = ip; ip = ic; ic = io; io = tmp; }
    }
    int sel = (deg - 1) % 3;
    cur = (sel == 0) ? a : (sel == 1) ? b : cur;
  };
  auto cholqr = [&]() {
    hipLaunchKernelGGL(k_syrk, dim3(25), dim3(256), 0, stream, Zb[cur], C);
    hipLaunchKernelGGL(k_cholinv, dim3(1), dim3(512), 0, stream, C, Rinv);
    int o = (cur + 1) % 6;
    hipLaunchKernelGGL(k_gemmSR, dim3(32), dim3(256), 0, stream, Zb[cur], Rinv, Zb[o]);
    cur = o;
  };
  auto rrmid = [&](double* cutp) {
    int y = (cur + 1) % 6;
    gemmGZ(G, Zb[cur], nullptr, Zb[y], nullptr, 1.f, 0.f, 0.f);   // Y = G S
    hipLaunchKernelGGL(k_xty, dim3(25), dim3(256), 0, stream, Zb[cur], Zb[y], Mm);
    hipLaunchKernelGGL(k_jacobi, dim3(1), dim3(1024), 0, stream,
                       Mm, U, perm, cutp, 2, 0);
  };
  auto rrfinal = [&](double* cutp) {
    int y = (cur + 1) % 6;
    gemmGZ(G, Zb[cur], nullptr, Zb[y], nullptr, 1.f, 0.f, 0.f);   // Y = G S
    hipLaunchKernelGGL(k_xty, dim3(25), dim3(256), 0, stream, Zb[cur], Zb[y], Mm);
    hipLaunchKernelGGL(k_jacobi, dim3(1), dim3(1024), 0, stream,
                       Mm, U, perm, cutp, 5, 1);
    hipLaunchKernelGGL(k_compose, dim3(16), dim3(256), 0, stream,
                       Zb[cur], U, perm, Vtop);
  };

  const float* hin = x;
  float* hout = hA;
  for (int l = 0; l < 3; l++) {
    hipLaunchKernelGGL(k_linT, dim3(GRID_ROWS), dim3(256), 0, stream,
                       hin, Wl[l], (const float*)nullptr, hl, 64, 0);
    hipMemsetAsync(mus, 0, 16 * 64 * 4, stream);
    hipLaunchKernelGGL(k_meanslot, dim3(16, 8), dim3(256), 0, stream, hl, src, mus);
    hipMemsetAsync(T, 0, (size_t)NB * NB * 4, stream);
    hipLaunchKernelGGL(k_gram, dim3(136, 5), dim3(256), 0, stream, hl, src, mus, T);
    hipLaunchKernelGGL(k_assembleG, dim3(4096), dim3(256), 0, stream, T, G);
    hipLaunchKernelGGL(k_cut0, dim3(1), dim3(256), 0, stream, G, scal);
    hipLaunchKernelGGL(k_gemmG2, dim3(16, 16), dim3(256), 0, stream, G, G2);
    cur = 0;
    hipLaunchKernelGGL(k_initS, dim3((NB * BSUB + 255) / 256), dim3(256), 0, stream, Zb[cur]);
    chunk2(6, &scal[1]); cholqr();          // T12 filter
    rrmid(&scal[2]);                        // writes scal[2]=cut, scal[3]=cut^2
    chunk2(7, &scal[3]); cholqr();          // T14
    chunk2(7, &scal[3]); cholqr();          // T14
    rrfinal(&scal[4]);
    hipLaunchKernelGGL(k_projlin, dim3(GRID_ROWS), dim3(256), 0, stream,
                       hl, src, Vtop, Wl[l], bl[l], hout);
    hin = hout;
    hout = (hout == hA) ? hB : hA;
  }
  hipLaunchKernelGGL(k_linT, dim3(GRID_ROWS), dim3(256), 0, stream,
                     hin, Wfc, bfc, hl, NCLS, 0);
  hipLaunchKernelGGL(k_logsoftmax, dim3((NNODES + 255) / 256), dim3(256), 0, stream,
                     hl, outp);
}